// Round 6
// baseline (1877.996 us; speedup 1.0000x reference)
//
#include <hip/hip_runtime.h>
#include <math.h>

#define HH 192
#define WW 192
#define HWP (192*192)
#define BB 4
#define CF 64
#define NC 7
#define OO 64
#define PIX_BLOCKS (HWP/256)   // 144

typedef float f32x16 __attribute__((ext_vector_type(16)));

// ---------------- standalone depthwise conv (fallback path) ----------------
template<int k>
__global__ __launch_bounds__(256)
void dw_kernel(const float* __restrict__ fea, const float* __restrict__ w,
               const float* __restrict__ bias, float* __restrict__ out) {
    int idx = blockIdx.x * 256 + threadIdx.x;   // over B*CF*HW
    if (idx >= BB * CF * HWP) return;
    int wpos = idx % WW;
    int hpos = (idx / WW) % HH;
    int plane = idx / HWP;        // b*CF + c
    int c = plane % CF;
    const float* f = fea + (size_t)plane * HWP;
    const int pad = k / 2;
    float acc = 0.f;
#pragma unroll
    for (int dy = 0; dy < k; ++dy) {
        int y = hpos + dy - pad;
        if (y < 0 || y >= HH) continue;
#pragma unroll
        for (int dx = 0; dx < k; ++dx) {
            int x = wpos + dx - pad;
            if (x < 0 || x >= WW) continue;
            acc += f[y * WW + x] * w[c * k * k + dy * k + dx];
        }
    }
    out[idx] = acc + bias[c];
}

// ---------------- fused dw conv for k=3 and k=5 (single fea pass) ----------
__global__ __launch_bounds__(256)
void dw35_kernel(const float* __restrict__ fea,
                 const float* __restrict__ w3, const float* __restrict__ b3,
                 const float* __restrict__ w5, const float* __restrict__ b5,
                 float* __restrict__ out3, float* __restrict__ out5) {
    int idx = blockIdx.x * 256 + threadIdx.x;
    if (idx >= BB * CF * HWP) return;
    int wpos = idx % WW;
    int hpos = (idx / WW) % HH;
    int plane = idx / HWP;
    int c = plane % CF;
    const float* f = fea + (size_t)plane * HWP;
    float nv[5][5];
#pragma unroll
    for (int dy = 0; dy < 5; ++dy) {
        int y = hpos + dy - 2;
        bool yv = (y >= 0) && (y < HH);
        int yc = min(max(y, 0), HH - 1);
#pragma unroll
        for (int dx = 0; dx < 5; ++dx) {
            int x = wpos + dx - 2;
            bool v = yv && (x >= 0) && (x < WW);
            int xc = min(max(x, 0), WW - 1);
            float val = f[yc * WW + xc];
            nv[dy][dx] = v ? val : 0.f;
        }
    }
    float a3 = 0.f, a5 = 0.f;
#pragma unroll
    for (int dy = 0; dy < 5; ++dy)
#pragma unroll
        for (int dx = 0; dx < 5; ++dx)
            a5 += nv[dy][dx] * w5[c * 25 + dy * 5 + dx];
#pragma unroll
    for (int dy = 0; dy < 3; ++dy)
#pragma unroll
        for (int dx = 0; dx < 3; ++dx)
            a3 += nv[dy + 1][dx + 1] * w3[c * 9 + dy * 3 + dx];
    out3[idx] = a3 + b3[c];
    out5[idx] = a5 + b5[c];
}

// ---------------- generic small transpose (rows,cols) -> (cols,rows) ------
__global__ void transpose_kernel(const float* __restrict__ in, float* __restrict__ out,
                                 int rows, int cols) {
    int idx = blockIdx.x * 256 + threadIdx.x;
    if (idx >= rows * cols) return;
    int r = idx / cols, c = idx % cols;
    out[c * rows + r] = in[idx];
}

// ---------------- branch kernel with LDS-staged pw weights ----------------
// Round-4 lesson: weight stream through L1/L2 is the per-iteration stall
// (occupancy x4 changed nothing). Stage the pw slab in LDS once per block;
// inner loop reads are uniform-address ds_read broadcasts (conflict-free).
// k=5 is tap-split in half (r [0,88) -> outbuf t2 raw, [88,175) -> part1 raw).
template<int k>
__global__ __launch_bounds__(256)
void branch_lds_kernel(const float* __restrict__ fea,
                       const float* __restrict__ dw_w0, const float* __restrict__ dw_b0,
                       const float* __restrict__ dwsrc,
                       const float* __restrict__ pw_w, const float* __restrict__ pw_b,
                       const float* __restrict__ inputs,
                       const float* __restrict__ dcn_wt, const float* __restrict__ dcn_b,
                       float* __restrict__ outbuf, float* __restrict__ part1, int t) {
    constexpr int K = k * k;
    constexpr int T = NC * K;
    constexpr int pad = k / 2;
    extern __shared__ float lds[];

    int gid = blockIdx.x;
    int r0 = 0, r1 = T, half = 0;
    if (k == 5) {
        half = gid / (BB * PIX_BLOCKS);
        gid -= half * (BB * PIX_BLOCKS);
        if (half == 0) { r0 = 0; r1 = 88; } else { r0 = 88; r1 = 175; }
    }
    const int nr = r1 - r0;

    // ---- stage pw weights: yx rows [2*r0, 2*r1) then m rows [2T+r0, 2T+r1)
    {
        const float4* s_yx = (const float4*)(pw_w + (size_t)(2 * r0) * CF);
        const float4* s_m  = (const float4*)(pw_w + (size_t)(2 * T + r0) * CF);
        float4* d_yx = (float4*)lds;
        float4* d_m  = (float4*)(lds + (size_t)nr * 128);
        int n_yx = nr * 32;   // float4 count
        int n_m  = nr * 16;
        for (int i = threadIdx.x; i < n_yx; i += 256) d_yx[i] = s_yx[i];
        for (int i = threadIdx.x; i < n_m; i += 256)  d_m[i]  = s_m[i];
    }
    __syncthreads();
    const float* lyx = lds;
    const float* lm  = lds + (size_t)nr * 128;

    int b = gid / PIX_BLOCKS;
    int p = (gid % PIX_BLOCKS) * 256 + threadIdx.x;
    int h = p / WW, wq = p % WW;
    const float* inb = inputs + (size_t)b * NC * HWP;

    // ---- per-pixel dw vector
    f32x16 dwv0, dwv1, dwv2, dwv3;
    if (k == 1) {
        const float* fp = fea + (size_t)(b * CF) * HWP + p;
#pragma unroll
        for (int j = 0; j < 16; ++j) dwv0[j] = fp[(size_t)j * HWP] * dw_w0[j] + dw_b0[j];
#pragma unroll
        for (int j = 0; j < 16; ++j) dwv1[j] = fp[(size_t)(16 + j) * HWP] * dw_w0[16 + j] + dw_b0[16 + j];
#pragma unroll
        for (int j = 0; j < 16; ++j) dwv2[j] = fp[(size_t)(32 + j) * HWP] * dw_w0[32 + j] + dw_b0[32 + j];
#pragma unroll
        for (int j = 0; j < 16; ++j) dwv3[j] = fp[(size_t)(48 + j) * HWP] * dw_w0[48 + j] + dw_b0[48 + j];
    } else {
        const float* dwp = dwsrc + (size_t)(b * CF) * HWP + p;
#pragma unroll
        for (int j = 0; j < 16; ++j) dwv0[j] = dwp[(size_t)j * HWP];
#pragma unroll
        for (int j = 0; j < 16; ++j) dwv1[j] = dwp[(size_t)(16 + j) * HWP];
#pragma unroll
        for (int j = 0; j < 16; ++j) dwv2[j] = dwp[(size_t)(32 + j) * HWP];
#pragma unroll
        for (int j = 0; j < 16; ++j) dwv3[j] = dwp[(size_t)(48 + j) * HWP];
    }

    f32x16 acc0, acc1, acc2, acc3;
#pragma unroll
    for (int j = 0; j < 16; ++j) { acc0[j] = 0.f; acc1[j] = 0.f; acc2[j] = 0.f; acc3[j] = 0.f; }

    int c = r0 / K;
    int kk = r0 % K;
    int ky = kk / k, kx = kk % k;

    for (int i = 0; i < nr; ++i) {
        int r = r0 + i;
        const float* wy = lyx + i * 128;
        const float* wx = wy + 64;
        const float* wm = lm + i * 64;
        const float* inc_ = inb + (size_t)c * HWP;
        float oy = pw_b[2 * r], ox = pw_b[2 * r + 1], om = pw_b[2 * T + r];
#pragma unroll
        for (int j = 0; j < 16; ++j) {
            oy += wy[j] * dwv0[j];  ox += wx[j] * dwv0[j];  om += wm[j] * dwv0[j];
        }
#pragma unroll
        for (int j = 0; j < 16; ++j) {
            oy += wy[16 + j] * dwv1[j];  ox += wx[16 + j] * dwv1[j];  om += wm[16 + j] * dwv1[j];
        }
#pragma unroll
        for (int j = 0; j < 16; ++j) {
            oy += wy[32 + j] * dwv2[j];  ox += wx[32 + j] * dwv2[j];  om += wm[32 + j] * dwv2[j];
        }
#pragma unroll
        for (int j = 0; j < 16; ++j) {
            oy += wy[48 + j] * dwv3[j];  ox += wx[48 + j] * dwv3[j];  om += wm[48 + j] * dwv3[j];
        }
        float m = 1.f / (1.f + __expf(-om));
        float py = oy + (float)(ky + h - pad);
        float px = ox + (float)(kx + wq - pad);
        float y0 = floorf(py), x0 = floorf(px);
        float wyf = py - y0, wxf = px - x0;
        int iy0 = (int)y0, ix0 = (int)x0;
        bool y0v = (iy0 >= 0) && (iy0 < HH);
        bool y1v = (iy0 + 1 >= 0) && (iy0 + 1 < HH);
        bool x0v = (ix0 >= 0) && (ix0 < WW);
        bool x1v = (ix0 + 1 >= 0) && (ix0 + 1 < WW);
        int yc0 = min(max(iy0, 0), HH - 1), yc1 = min(max(iy0 + 1, 0), HH - 1);
        int xc0 = min(max(ix0, 0), WW - 1), xc1 = min(max(ix0 + 1, 0), WW - 1);
        float v00 = 0.f, v01 = 0.f, v10 = 0.f, v11 = 0.f;
        if (y0v) {
            if (x0v) v00 = inc_[yc0 * WW + xc0];
            if (x1v) v01 = inc_[yc0 * WW + xc1];
        }
        if (y1v) {
            if (x0v) v10 = inc_[yc1 * WW + xc0];
            if (x1v) v11 = inc_[yc1 * WW + xc1];
        }
        float s = (v00 * (1.f - wyf) * (1.f - wxf) + v01 * (1.f - wyf) * wxf +
                   v10 * wyf * (1.f - wxf) + v11 * wyf * wxf) * m;
        const float* dt = dcn_wt + (size_t)r * OO;   // global, uniform, independent
#pragma unroll
        for (int j = 0; j < 16; ++j) acc0[j] += s * dt[j];
#pragma unroll
        for (int j = 0; j < 16; ++j) acc1[j] += s * dt[16 + j];
#pragma unroll
        for (int j = 0; j < 16; ++j) acc2[j] += s * dt[32 + j];
#pragma unroll
        for (int j = 0; j < 16; ++j) acc3[j] += s * dt[48 + j];
        if (++kx == k) { kx = 0; if (++ky == k) { ky = 0; ++c; } }
    }

    if (k == 5) {
        float* op = (half == 0)
            ? outbuf + (size_t)((b * 3 + 2) * OO) * HWP + p
            : part1 + (size_t)(b * OO) * HWP + p;
#pragma unroll
        for (int j = 0; j < 16; ++j) op[(size_t)j * HWP] = acc0[j];
#pragma unroll
        for (int j = 0; j < 16; ++j) op[(size_t)(16 + j) * HWP] = acc1[j];
#pragma unroll
        for (int j = 0; j < 16; ++j) op[(size_t)(32 + j) * HWP] = acc2[j];
#pragma unroll
        for (int j = 0; j < 16; ++j) op[(size_t)(48 + j) * HWP] = acc3[j];
    } else {
        float* op = outbuf + (size_t)((b * 3 + t) * OO) * HWP + p;
#pragma unroll
        for (int j = 0; j < 16; ++j) { float v = acc0[j] + dcn_b[j];      op[(size_t)j * HWP] = v > 0.f ? v : 0.f; }
#pragma unroll
        for (int j = 0; j < 16; ++j) { float v = acc1[j] + dcn_b[16 + j]; op[(size_t)(16 + j) * HWP] = v > 0.f ? v : 0.f; }
#pragma unroll
        for (int j = 0; j < 16; ++j) { float v = acc2[j] + dcn_b[32 + j]; op[(size_t)(32 + j) * HWP] = v > 0.f ? v : 0.f; }
#pragma unroll
        for (int j = 0; j < 16; ++j) { float v = acc3[j] + dcn_b[48 + j]; op[(size_t)(48 + j) * HWP] = v > 0.f ? v : 0.f; }
    }
}

// ---------------- combine: outbuf t2 = relu(partA + partB + bias) ---------
__global__ __launch_bounds__(256)
void combine_kernel(float* __restrict__ outbuf, const float* __restrict__ part1,
                    const float* __restrict__ dcn_b2) {
    int blk = blockIdx.x;
    int b = blk / PIX_BLOCKS;
    int p = (blk % PIX_BLOCKS) * 256 + threadIdx.x;
    float* op = outbuf + (size_t)((b * 3 + 2) * OO) * HWP + p;
    const float* pp = part1 + (size_t)(b * OO) * HWP + p;
#pragma unroll 8
    for (int o = 0; o < OO; ++o) {
        float v = op[(size_t)o * HWP] + pp[(size_t)o * HWP] + dcn_b2[o];
        op[(size_t)o * HWP] = v > 0.f ? v : 0.f;
    }
}

// ---------------- attention: per-block partial sums of relu(attn pw) ------
__global__ __launch_bounds__(256)
void attn_sum_kernel(const float* __restrict__ outbuf, const float* __restrict__ attn_wt,
                     const float* __restrict__ attn_b, float* __restrict__ partial) {
    int blk = blockIdx.x;
    int b = blk / PIX_BLOCKS;
    int pb = blk % PIX_BLOCKS;
    int p = pb * 256 + threadIdx.x;
    const float* ob = outbuf + (size_t)(b * 192) * HWP + p;
    f32x16 a0, a1, a2, a3;
#pragma unroll
    for (int j = 0; j < 16; ++j) {
        a0[j] = attn_b[j]; a1[j] = attn_b[16 + j]; a2[j] = attn_b[32 + j]; a3[j] = attn_b[48 + j];
    }
    for (int c = 0; c < 192; ++c) {
        float v = ob[(size_t)c * HWP];
        const float* wt = attn_wt + c * OO;
#pragma unroll
        for (int j = 0; j < 16; ++j) a0[j] += v * wt[j];
#pragma unroll
        for (int j = 0; j < 16; ++j) a1[j] += v * wt[16 + j];
#pragma unroll
        for (int j = 0; j < 16; ++j) a2[j] += v * wt[32 + j];
#pragma unroll
        for (int j = 0; j < 16; ++j) a3[j] += v * wt[48 + j];
    }
    __shared__ float red[4][OO];
    int lane = threadIdx.x & 63, wv = threadIdx.x >> 6;
#pragma unroll
    for (int o = 0; o < OO; ++o) {
        float v = (o < 16) ? a0[o & 15] : (o < 32) ? a1[o & 15] : (o < 48) ? a2[o & 15] : a3[o & 15];
        v = v > 0.f ? v : 0.f;
        v += __shfl_down(v, 32);
        v += __shfl_down(v, 16);
        v += __shfl_down(v, 8);
        v += __shfl_down(v, 4);
        v += __shfl_down(v, 2);
        v += __shfl_down(v, 1);
        if (lane == 0) red[wv][o] = v;
    }
    __syncthreads();
    if (threadIdx.x < OO) {
        int o = threadIdx.x;
        partial[(size_t)(b * PIX_BLOCKS + pb) * OO + o] =
            red[0][o] + red[1][o] + red[2][o] + red[3][o];
    }
}

// ---------------- attention finish: mean -> fc(relu) -> per-branch scales -
__global__ void attn_finish_kernel(const float* __restrict__ partial,
                                   const float* __restrict__ fc_w, const float* __restrict__ fc_b,
                                   const float* __restrict__ fcs_w0, const float* __restrict__ fcs_b0,
                                   const float* __restrict__ fcs_w1, const float* __restrict__ fcs_b1,
                                   const float* __restrict__ fcs_w2, const float* __restrict__ fcs_b2,
                                   float* __restrict__ atts) {
    int b = blockIdx.x;
    __shared__ float attm[OO];
    __shared__ float fcv[32];
    int tid = threadIdx.x;   // 64 threads
    if (tid < OO) {
        float s = 0.f;
        for (int blk = 0; blk < PIX_BLOCKS; ++blk)
            s += partial[(size_t)(b * PIX_BLOCKS + blk) * OO + tid];
        attm[tid] = s / (float)HWP;
    }
    __syncthreads();
    if (tid < 32) {
        float s = fc_b[tid];
        for (int o = 0; o < OO; ++o) s += fc_w[tid * OO + o] * attm[o];
        fcv[tid] = s > 0.f ? s : 0.f;
    }
    __syncthreads();
    if (tid < OO) {
        {
            float s = fcs_b0[tid];
            for (int j = 0; j < 32; ++j) s += fcs_w0[tid * 32 + j] * fcv[j];
            atts[b * 192 + 0 * OO + tid] = s;
        }
        {
            float s = fcs_b1[tid];
            for (int j = 0; j < 32; ++j) s += fcs_w1[tid * 32 + j] * fcv[j];
            atts[b * 192 + 1 * OO + tid] = s;
        }
        {
            float s = fcs_b2[tid];
            for (int j = 0; j < 32; ++j) s += fcs_w2[tid * 32 + j] * fcv[j];
            atts[b * 192 + 2 * OO + tid] = s;
        }
    }
}

// ---------------- final: scale + 1x1 conv + relu ----------------
__global__ __launch_bounds__(256)
void final_kernel(const float* __restrict__ outbuf, const float* __restrict__ atts,
                  const float* __restrict__ conv_wt, const float* __restrict__ conv_b,
                  float* __restrict__ out) {
    int blk = blockIdx.x;
    int b = blk / PIX_BLOCKS;
    int p = (blk % PIX_BLOCKS) * 256 + threadIdx.x;
    const float* ob = outbuf + (size_t)(b * 192) * HWP + p;
    const float* at = atts + b * 192;
    f32x16 a0, a1, a2, a3;
#pragma unroll
    for (int j = 0; j < 16; ++j) {
        a0[j] = conv_b[j]; a1[j] = conv_b[16 + j]; a2[j] = conv_b[32 + j]; a3[j] = conv_b[48 + j];
    }
    for (int c = 0; c < 192; ++c) {
        float v = ob[(size_t)c * HWP] * at[c];
        const float* wt = conv_wt + c * OO;
#pragma unroll
        for (int j = 0; j < 16; ++j) a0[j] += v * wt[j];
#pragma unroll
        for (int j = 0; j < 16; ++j) a1[j] += v * wt[16 + j];
#pragma unroll
        for (int j = 0; j < 16; ++j) a2[j] += v * wt[32 + j];
#pragma unroll
        for (int j = 0; j < 16; ++j) a3[j] += v * wt[48 + j];
    }
    float* op = out + (size_t)(b * OO) * HWP + p;
#pragma unroll
    for (int j = 0; j < 16; ++j) op[(size_t)j * HWP] = a0[j] > 0.f ? a0[j] : 0.f;
#pragma unroll
    for (int j = 0; j < 16; ++j) op[(size_t)(16 + j) * HWP] = a1[j] > 0.f ? a1[j] : 0.f;
#pragma unroll
    for (int j = 0; j < 16; ++j) op[(size_t)(32 + j) * HWP] = a2[j] > 0.f ? a2[j] : 0.f;
#pragma unroll
    for (int j = 0; j < 16; ++j) op[(size_t)(48 + j) * HWP] = a3[j] > 0.f ? a3[j] : 0.f;
}

extern "C" void kernel_launch(void* const* d_in, const int* in_sizes, int n_in,
                              void* d_out, int out_size, void* d_ws, size_t ws_size,
                              hipStream_t stream) {
    const float* fea    = (const float*)d_in[0];
    const float* inputs = (const float*)d_in[1];
    const float* dw_w[3]  = {(const float*)d_in[2],  (const float*)d_in[8],  (const float*)d_in[14]};
    const float* dw_b[3]  = {(const float*)d_in[3],  (const float*)d_in[9],  (const float*)d_in[15]};
    const float* pw_w[3]  = {(const float*)d_in[4],  (const float*)d_in[10], (const float*)d_in[16]};
    const float* pw_b[3]  = {(const float*)d_in[5],  (const float*)d_in[11], (const float*)d_in[17]};
    const float* dcn_w[3] = {(const float*)d_in[6],  (const float*)d_in[12], (const float*)d_in[18]};
    const float* dcn_b[3] = {(const float*)d_in[7],  (const float*)d_in[13], (const float*)d_in[19]};
    const float* attn_w = (const float*)d_in[20];
    const float* attn_b = (const float*)d_in[21];
    const float* fc_w   = (const float*)d_in[22];
    const float* fc_b   = (const float*)d_in[23];
    const float* fcs_w[3] = {(const float*)d_in[24], (const float*)d_in[26], (const float*)d_in[28]};
    const float* fcs_b[3] = {(const float*)d_in[25], (const float*)d_in[27], (const float*)d_in[29]};
    const float* conv_w = (const float*)d_in[30];
    const float* conv_b = (const float*)d_in[31];
    float* out = (float*)d_out;

    const size_t F_OUTBUF = 28311552, F_DW = 9437184;
    const size_t F_SMALL = 36864 + 768 + 512 + 4096 + 11264 + 12288 + 12288;
    size_t need_big = (F_OUTBUF + 2 * F_DW + F_SMALL) * 4;
    bool big = ws_size >= need_big;

    float* W = (float*)d_ws;
    float* outbuf = W;            W += F_OUTBUF;
    float* dw3out, * dw5out;
    if (big) { dw3out = W; W += F_DW; dw5out = W; W += F_DW; }
    else     { dw3out = W; dw5out = W; W += F_DW; }
    float* partial = W;           W += 36864;
    float* atts = W;              W += 768;
    float* dcn_wt0 = W;           W += 512;
    float* dcn_wt1 = W;           W += 4096;
    float* dcn_wt2 = W;           W += 11264;
    float* attn_wt = W;           W += 12288;
    float* conv_wt = W;           W += 12288;
    float* part1 = out;           // d_out doubles as k5-partial; final_kernel rewrites it

    // weight transposes
    transpose_kernel<<<(192 * 64 + 255) / 256, 256, 0, stream>>>(attn_w, attn_wt, 64, 192);
    transpose_kernel<<<(192 * 64 + 255) / 256, 256, 0, stream>>>(conv_w, conv_wt, 64, 192);
    transpose_kernel<<<(7 * 64 + 255) / 256, 256, 0, stream>>>(dcn_w[0], dcn_wt0, 64, 7);
    transpose_kernel<<<(63 * 64 + 255) / 256, 256, 0, stream>>>(dcn_w[1], dcn_wt1, 64, 63);
    transpose_kernel<<<(175 * 64 + 255) / 256, 256, 0, stream>>>(dcn_w[2], dcn_wt2, 64, 175);

    const int dw_grid = (BB * CF * HWP) / 256;   // 36864
    const int pix_grid = BB * PIX_BLOCKS;        // 576

    const size_t lds_k1 = (size_t)7 * 192 * 4;    //  5376 B
    const size_t lds_k3 = (size_t)63 * 192 * 4;   // 48384 B
    const size_t lds_k5 = (size_t)88 * 192 * 4;   // 67584 B

    // k1 branch (independent of dw35)
    branch_lds_kernel<1><<<pix_grid, 256, lds_k1, stream>>>(
        fea, dw_w[0], dw_b[0], dw3out, pw_w[0], pw_b[0],
        inputs, dcn_wt0, dcn_b[0], outbuf, part1, 0);

    if (big) {
        dw35_kernel<<<dw_grid, 256, 0, stream>>>(fea, dw_w[1], dw_b[1], dw_w[2], dw_b[2],
                                                 dw3out, dw5out);
        branch_lds_kernel<3><<<pix_grid, 256, lds_k3, stream>>>(
            fea, dw_w[0], dw_b[0], dw3out, pw_w[1], pw_b[1],
            inputs, dcn_wt1, dcn_b[1], outbuf, part1, 1);
        branch_lds_kernel<5><<<2 * pix_grid, 256, lds_k5, stream>>>(
            fea, dw_w[0], dw_b[0], dw5out, pw_w[2], pw_b[2],
            inputs, dcn_wt2, dcn_b[2], outbuf, part1, 2);
    } else {
        dw_kernel<3><<<dw_grid, 256, 0, stream>>>(fea, dw_w[1], dw_b[1], dw3out);
        branch_lds_kernel<3><<<pix_grid, 256, lds_k3, stream>>>(
            fea, dw_w[0], dw_b[0], dw3out, pw_w[1], pw_b[1],
            inputs, dcn_wt1, dcn_b[1], outbuf, part1, 1);
        dw_kernel<5><<<dw_grid, 256, 0, stream>>>(fea, dw_w[2], dw_b[2], dw5out);
        branch_lds_kernel<5><<<2 * pix_grid, 256, lds_k5, stream>>>(
            fea, dw_w[0], dw_b[0], dw5out, pw_w[2], pw_b[2],
            inputs, dcn_wt2, dcn_b[2], outbuf, part1, 2);
    }
    combine_kernel<<<pix_grid, 256, 0, stream>>>(outbuf, part1, dcn_b[2]);

    // attention + final
    attn_sum_kernel<<<pix_grid, 256, 0, stream>>>(outbuf, attn_wt, attn_b, partial);
    attn_finish_kernel<<<BB, 64, 0, stream>>>(partial, fc_w, fc_b,
                                              fcs_w[0], fcs_b[0], fcs_w[1], fcs_b[1],
                                              fcs_w[2], fcs_b[2], atts);
    final_kernel<<<pix_grid, 256, 0, stream>>>(outbuf, atts, conv_wt, conv_b, out);
}

// Round 7
// 1008.742 us; speedup vs baseline: 1.8617x; 1.8617x over previous
//
#include <hip/hip_runtime.h>
#include <math.h>

#define HH 192
#define WW 192
#define HWP (192*192)
#define BB 4
#define CF 64
#define NC 7
#define OO 64
#define NTOT (BB*HWP)          // 147456
#define PIX_BLOCKS (HWP/256)   // 144

typedef float f32x16 __attribute__((ext_vector_type(16)));
typedef float f32x4  __attribute__((ext_vector_type(4)));

// ---------------- depthwise conv (SAME, groups=C) ----------------
template<int k>
__global__ __launch_bounds__(256)
void dw_kernel(const float* __restrict__ fea, const float* __restrict__ w,
               const float* __restrict__ bias, float* __restrict__ out) {
    int idx = blockIdx.x * 256 + threadIdx.x;
    if (idx >= BB * CF * HWP) return;
    int wpos = idx % WW;
    int hpos = (idx / WW) % HH;
    int plane = idx / HWP;
    int c = plane % CF;
    const float* f = fea + (size_t)plane * HWP;
    const int pad = k / 2;
    float acc = 0.f;
#pragma unroll
    for (int dy = 0; dy < k; ++dy) {
        int y = hpos + dy - pad;
        if (y < 0 || y >= HH) continue;
#pragma unroll
        for (int dx = 0; dx < k; ++dx) {
            int x = wpos + dx - pad;
            if (x < 0 || x >= WW) continue;
            acc += f[y * WW + x] * w[c * k * k + dy * k + dx];
        }
    }
    out[idx] = acc + bias[c];
}

// ---------------- generic small transpose ----------------
__global__ void transpose_kernel(const float* __restrict__ in, float* __restrict__ out,
                                 int rows, int cols) {
    int idx = blockIdx.x * 256 + threadIdx.x;
    if (idx >= rows * cols) return;
    int r = idx / cols, c = idx % cols;
    out[c * rows + r] = in[idx];
}

// ---------------- pw GEMM: om[m][NTOT] = pw_w[src(m)][:] @ dw + pw_b -------
// dw layout [BB][CF][HWP]; n = b*HWP + p; BN=128 divides HWP. BM=64, K=64.
// A row mapping: m < n_yx -> src0+m (offset y/x rows), else src1+(m-n_yx) (mask rows).
__global__ __launch_bounds__(256)
void pw_gemm_kernel(const float* __restrict__ pw_w, const float* __restrict__ pw_b,
                    const float* __restrict__ dw, float* __restrict__ om,
                    int src0, int n_yx, int src1, int M) {
    __shared__ float As[64][68];    // [k][m], padded
    __shared__ float Bs[64][132];   // [k][n], padded (16B-align preserved)
    const int ntiles = NTOT / 128;
    int ntile = blockIdx.x % ntiles;
    int mtile = blockIdx.x / ntiles;
    int nb0 = ntile * 128;
    int mb0 = mtile * 64;
    int tid = threadIdx.x;

    // stage A (transpose to [k][m])
    {
        int m = tid & 63;
        int kq = tid >> 6;   // 0..3
        int gm = mb0 + m;
        int srow = (gm < M) ? ((gm < n_yx) ? (src0 + gm) : (src1 + (gm - n_yx))) : src0;
        const float* ap = pw_w + (size_t)srow * CF;
#pragma unroll
        for (int i = 0; i < 4; ++i) {
            int k0 = (kq * 4 + i) * 4;
            float4 v = *(const float4*)(ap + k0);
            As[k0 + 0][m] = v.x; As[k0 + 1][m] = v.y;
            As[k0 + 2][m] = v.z; As[k0 + 3][m] = v.w;
        }
    }
    // stage B
    {
        int b = nb0 / HWP;
        int p0 = nb0 % HWP;
        const float* bp = dw + (size_t)b * CF * HWP + p0;
#pragma unroll
        for (int i = 0; i < 8; ++i) {
            int idx = tid + i * 256;
            int kk = idx >> 5;
            int f4 = idx & 31;
            float4 v = *(const float4*)(bp + (size_t)kk * HWP + f4 * 4);
            *(float4*)&Bs[kk][f4 * 4] = v;
        }
    }
    __syncthreads();

    int tm = (tid & 15) * 4;
    int tn = (tid >> 4) * 8;
    f32x4 aA0 = 0.f, aA1 = 0.f, aB0 = 0.f, aB1 = 0.f;
    f32x4 aC0 = 0.f, aC1 = 0.f, aD0 = 0.f, aD1 = 0.f;
#pragma unroll 8
    for (int kk = 0; kk < 64; ++kk) {
        f32x4 a  = *(const f32x4*)&As[kk][tm];
        f32x4 b0 = *(const f32x4*)&Bs[kk][tn];
        f32x4 b1 = *(const f32x4*)&Bs[kk][tn + 4];
#pragma unroll
        for (int j = 0; j < 4; ++j) {
            aA0[j] += a[0] * b0[j];  aA1[j] += a[0] * b1[j];
            aB0[j] += a[1] * b0[j];  aB1[j] += a[1] * b1[j];
            aC0[j] += a[2] * b0[j];  aC1[j] += a[2] * b1[j];
            aD0[j] += a[3] * b0[j];  aD1[j] += a[3] * b1[j];
        }
    }
    // store (+bias), guard M
    {
        int gm = mb0 + tm;
        float* dst = om + (size_t)gm * NTOT + nb0 + tn;
        if (gm < M) {
            float bi = pw_b[(gm < n_yx) ? (src0 + gm) : (src1 + gm - n_yx)];
#pragma unroll
            for (int j = 0; j < 4; ++j) { dst[j] = aA0[j] + bi; dst[4 + j] = aA1[j] + bi; }
        }
        gm++; dst += NTOT;
        if (gm < M) {
            float bi = pw_b[(gm < n_yx) ? (src0 + gm) : (src1 + gm - n_yx)];
#pragma unroll
            for (int j = 0; j < 4; ++j) { dst[j] = aB0[j] + bi; dst[4 + j] = aB1[j] + bi; }
        }
        gm++; dst += NTOT;
        if (gm < M) {
            float bi = pw_b[(gm < n_yx) ? (src0 + gm) : (src1 + gm - n_yx)];
#pragma unroll
            for (int j = 0; j < 4; ++j) { dst[j] = aC0[j] + bi; dst[4 + j] = aC1[j] + bi; }
        }
        gm++; dst += NTOT;
        if (gm < M) {
            float bi = pw_b[(gm < n_yx) ? (src0 + gm) : (src1 + gm - n_yx)];
#pragma unroll
            for (int j = 0; j < 4; ++j) { dst[j] = aD0[j] + bi; dst[4 + j] = aD1[j] + bi; }
        }
    }
}

// ---------------- deformable sampling + dcn accumulation (tap chunk) ------
// om chunk layout: rows [0,2T) = oy/ox for taps t0..t1, rows [2T,3T) = mask raw.
// flags: 1 = first chunk (init acc), 2 = last chunk (add dcn bias + relu).
template<int k>
__global__ __launch_bounds__(256)
void dcn_sample_kernel(const float* __restrict__ om,
                       const float* __restrict__ inputs,
                       const float* __restrict__ dcn_wt,   // [7K][64]
                       const float* __restrict__ dcn_b,
                       float* __restrict__ outbuf, int t_slot,
                       int t0, int t1, int flags) {
    constexpr int K = k * k;
    constexpr int pad = k / 2;
    int n = blockIdx.x * 256 + threadIdx.x;
    int b = n / HWP, p = n % HWP;
    int h = p / WW, wq = p % WW;
    const int T = t1 - t0;
    const float* inb = inputs + (size_t)b * NC * HWP;
    float* op = outbuf + (size_t)((b * 3 + t_slot) * OO) * HWP + p;

    f32x16 acc0, acc1, acc2, acc3;
    if (flags & 1) {
#pragma unroll
        for (int j = 0; j < 16; ++j) { acc0[j] = 0.f; acc1[j] = 0.f; acc2[j] = 0.f; acc3[j] = 0.f; }
    } else {
#pragma unroll
        for (int j = 0; j < 16; ++j) acc0[j] = op[(size_t)j * HWP];
#pragma unroll
        for (int j = 0; j < 16; ++j) acc1[j] = op[(size_t)(16 + j) * HWP];
#pragma unroll
        for (int j = 0; j < 16; ++j) acc2[j] = op[(size_t)(32 + j) * HWP];
#pragma unroll
        for (int j = 0; j < 16; ++j) acc3[j] = op[(size_t)(48 + j) * HWP];
    }

    for (int i = 0; i < T; ++i) {
        int r = t0 + i;
        float oy = om[(size_t)(2 * i) * NTOT + n];
        float ox = om[(size_t)(2 * i + 1) * NTOT + n];
        float mr = om[(size_t)(2 * T + i) * NTOT + n];
        int c = r / K;
        int kk = r - c * K;
        int ky = kk / k, kx = kk - ky * k;
        const float* inc_ = inb + (size_t)c * HWP;
        float m = 1.f / (1.f + __expf(-mr));
        float py = oy + (float)(ky + h - pad);
        float px = ox + (float)(kx + wq - pad);
        float y0 = floorf(py), x0 = floorf(px);
        float wyf = py - y0, wxf = px - x0;
        int iy0 = (int)y0, ix0 = (int)x0;
        bool y0v = (iy0 >= 0) && (iy0 < HH);
        bool y1v = (iy0 + 1 >= 0) && (iy0 + 1 < HH);
        bool x0v = (ix0 >= 0) && (ix0 < WW);
        bool x1v = (ix0 + 1 >= 0) && (ix0 + 1 < WW);
        int yc0 = min(max(iy0, 0), HH - 1), yc1 = min(max(iy0 + 1, 0), HH - 1);
        int xc0 = min(max(ix0, 0), WW - 1), xc1 = min(max(ix0 + 1, 0), WW - 1);
        float v00 = 0.f, v01 = 0.f, v10 = 0.f, v11 = 0.f;
        if (y0v) {
            if (x0v) v00 = inc_[yc0 * WW + xc0];
            if (x1v) v01 = inc_[yc0 * WW + xc1];
        }
        if (y1v) {
            if (x0v) v10 = inc_[yc1 * WW + xc0];
            if (x1v) v11 = inc_[yc1 * WW + xc1];
        }
        float s = (v00 * (1.f - wyf) * (1.f - wxf) + v01 * (1.f - wyf) * wxf +
                   v10 * wyf * (1.f - wxf) + v11 * wyf * wxf) * m;
        const float* dt = dcn_wt + (size_t)r * OO;   // uniform -> scalar loads
#pragma unroll
        for (int j = 0; j < 16; ++j) acc0[j] += s * dt[j];
#pragma unroll
        for (int j = 0; j < 16; ++j) acc1[j] += s * dt[16 + j];
#pragma unroll
        for (int j = 0; j < 16; ++j) acc2[j] += s * dt[32 + j];
#pragma unroll
        for (int j = 0; j < 16; ++j) acc3[j] += s * dt[48 + j];
    }

    if (flags & 2) {
#pragma unroll
        for (int j = 0; j < 16; ++j) { float v = acc0[j] + dcn_b[j];      op[(size_t)j * HWP] = v > 0.f ? v : 0.f; }
#pragma unroll
        for (int j = 0; j < 16; ++j) { float v = acc1[j] + dcn_b[16 + j]; op[(size_t)(16 + j) * HWP] = v > 0.f ? v : 0.f; }
#pragma unroll
        for (int j = 0; j < 16; ++j) { float v = acc2[j] + dcn_b[32 + j]; op[(size_t)(32 + j) * HWP] = v > 0.f ? v : 0.f; }
#pragma unroll
        for (int j = 0; j < 16; ++j) { float v = acc3[j] + dcn_b[48 + j]; op[(size_t)(48 + j) * HWP] = v > 0.f ? v : 0.f; }
    } else {
#pragma unroll
        for (int j = 0; j < 16; ++j) op[(size_t)j * HWP] = acc0[j];
#pragma unroll
        for (int j = 0; j < 16; ++j) op[(size_t)(16 + j) * HWP] = acc1[j];
#pragma unroll
        for (int j = 0; j < 16; ++j) op[(size_t)(32 + j) * HWP] = acc2[j];
#pragma unroll
        for (int j = 0; j < 16; ++j) op[(size_t)(48 + j) * HWP] = acc3[j];
    }
}

// ---------------- k=1 branch: fused elementwise dw + 7-tap deform ---------
__global__ __launch_bounds__(256)
void branch_k1_kernel(const float* __restrict__ fea,
                      const float* __restrict__ dw_w0, const float* __restrict__ dw_b0,
                      const float* __restrict__ pw_w, const float* __restrict__ pw_b,
                      const float* __restrict__ inputs,
                      const float* __restrict__ dcn_wt, const float* __restrict__ dcn_b,
                      float* __restrict__ outbuf) {
    __shared__ float lw[21 * 64];
    for (int i = threadIdx.x; i < 21 * 16; i += 256)
        ((float4*)lw)[i] = ((const float4*)pw_w)[i];
    __syncthreads();
    int gid = blockIdx.x;
    int b = gid / PIX_BLOCKS;
    int p = (gid % PIX_BLOCKS) * 256 + threadIdx.x;
    int h = p / WW, wq = p % WW;
    const float* inb = inputs + (size_t)b * NC * HWP;

    f32x16 dwv0, dwv1, dwv2, dwv3;
    {
        const float* fp = fea + (size_t)(b * CF) * HWP + p;
#pragma unroll
        for (int j = 0; j < 16; ++j) dwv0[j] = fp[(size_t)j * HWP] * dw_w0[j] + dw_b0[j];
#pragma unroll
        for (int j = 0; j < 16; ++j) dwv1[j] = fp[(size_t)(16 + j) * HWP] * dw_w0[16 + j] + dw_b0[16 + j];
#pragma unroll
        for (int j = 0; j < 16; ++j) dwv2[j] = fp[(size_t)(32 + j) * HWP] * dw_w0[32 + j] + dw_b0[32 + j];
#pragma unroll
        for (int j = 0; j < 16; ++j) dwv3[j] = fp[(size_t)(48 + j) * HWP] * dw_w0[48 + j] + dw_b0[48 + j];
    }
    f32x16 acc0, acc1, acc2, acc3;
#pragma unroll
    for (int j = 0; j < 16; ++j) { acc0[j] = 0.f; acc1[j] = 0.f; acc2[j] = 0.f; acc3[j] = 0.f; }

    for (int r = 0; r < NC; ++r) {
        const float* wy = lw + (2 * r) * 64;
        const float* wx = wy + 64;
        const float* wm = lw + (14 + r) * 64;
        const float* inc_ = inb + (size_t)r * HWP;
        float oy = pw_b[2 * r], ox = pw_b[2 * r + 1], om = pw_b[14 + r];
#pragma unroll
        for (int j = 0; j < 16; ++j) { oy += wy[j] * dwv0[j];      ox += wx[j] * dwv0[j];      om += wm[j] * dwv0[j]; }
#pragma unroll
        for (int j = 0; j < 16; ++j) { oy += wy[16 + j] * dwv1[j]; ox += wx[16 + j] * dwv1[j]; om += wm[16 + j] * dwv1[j]; }
#pragma unroll
        for (int j = 0; j < 16; ++j) { oy += wy[32 + j] * dwv2[j]; ox += wx[32 + j] * dwv2[j]; om += wm[32 + j] * dwv2[j]; }
#pragma unroll
        for (int j = 0; j < 16; ++j) { oy += wy[48 + j] * dwv3[j]; ox += wx[48 + j] * dwv3[j]; om += wm[48 + j] * dwv3[j]; }
        float m = 1.f / (1.f + __expf(-om));
        float py = oy + (float)h;
        float px = ox + (float)wq;
        float y0 = floorf(py), x0 = floorf(px);
        float wyf = py - y0, wxf = px - x0;
        int iy0 = (int)y0, ix0 = (int)x0;
        bool y0v = (iy0 >= 0) && (iy0 < HH);
        bool y1v = (iy0 + 1 >= 0) && (iy0 + 1 < HH);
        bool x0v = (ix0 >= 0) && (ix0 < WW);
        bool x1v = (ix0 + 1 >= 0) && (ix0 + 1 < WW);
        int yc0 = min(max(iy0, 0), HH - 1), yc1 = min(max(iy0 + 1, 0), HH - 1);
        int xc0 = min(max(ix0, 0), WW - 1), xc1 = min(max(ix0 + 1, 0), WW - 1);
        float v00 = 0.f, v01 = 0.f, v10 = 0.f, v11 = 0.f;
        if (y0v) {
            if (x0v) v00 = inc_[yc0 * WW + xc0];
            if (x1v) v01 = inc_[yc0 * WW + xc1];
        }
        if (y1v) {
            if (x0v) v10 = inc_[yc1 * WW + xc0];
            if (x1v) v11 = inc_[yc1 * WW + xc1];
        }
        float s = (v00 * (1.f - wyf) * (1.f - wxf) + v01 * (1.f - wyf) * wxf +
                   v10 * wyf * (1.f - wxf) + v11 * wyf * wxf) * m;
        const float* dt = dcn_wt + (size_t)r * OO;
#pragma unroll
        for (int j = 0; j < 16; ++j) acc0[j] += s * dt[j];
#pragma unroll
        for (int j = 0; j < 16; ++j) acc1[j] += s * dt[16 + j];
#pragma unroll
        for (int j = 0; j < 16; ++j) acc2[j] += s * dt[32 + j];
#pragma unroll
        for (int j = 0; j < 16; ++j) acc3[j] += s * dt[48 + j];
    }
    float* op = outbuf + (size_t)(b * 3 * OO) * HWP + p;
#pragma unroll
    for (int j = 0; j < 16; ++j) { float v = acc0[j] + dcn_b[j];      op[(size_t)j * HWP] = v > 0.f ? v : 0.f; }
#pragma unroll
    for (int j = 0; j < 16; ++j) { float v = acc1[j] + dcn_b[16 + j]; op[(size_t)(16 + j) * HWP] = v > 0.f ? v : 0.f; }
#pragma unroll
    for (int j = 0; j < 16; ++j) { float v = acc2[j] + dcn_b[32 + j]; op[(size_t)(32 + j) * HWP] = v > 0.f ? v : 0.f; }
#pragma unroll
    for (int j = 0; j < 16; ++j) { float v = acc3[j] + dcn_b[48 + j]; op[(size_t)(48 + j) * HWP] = v > 0.f ? v : 0.f; }
}

// ---------------- attention: per-block partial sums of relu(attn pw) ------
__global__ __launch_bounds__(256)
void attn_sum_kernel(const float* __restrict__ outbuf, const float* __restrict__ attn_wt,
                     const float* __restrict__ attn_b, float* __restrict__ partial) {
    int blk = blockIdx.x;
    int b = blk / PIX_BLOCKS;
    int pb = blk % PIX_BLOCKS;
    int p = pb * 256 + threadIdx.x;
    const float* ob = outbuf + (size_t)(b * 192) * HWP + p;
    f32x16 a0, a1, a2, a3;
#pragma unroll
    for (int j = 0; j < 16; ++j) {
        a0[j] = attn_b[j]; a1[j] = attn_b[16 + j]; a2[j] = attn_b[32 + j]; a3[j] = attn_b[48 + j];
    }
    for (int c = 0; c < 192; ++c) {
        float v = ob[(size_t)c * HWP];
        const float* wt = attn_wt + c * OO;
#pragma unroll
        for (int j = 0; j < 16; ++j) a0[j] += v * wt[j];
#pragma unroll
        for (int j = 0; j < 16; ++j) a1[j] += v * wt[16 + j];
#pragma unroll
        for (int j = 0; j < 16; ++j) a2[j] += v * wt[32 + j];
#pragma unroll
        for (int j = 0; j < 16; ++j) a3[j] += v * wt[48 + j];
    }
    __shared__ float red[4][OO];
    int lane = threadIdx.x & 63, wv = threadIdx.x >> 6;
#pragma unroll
    for (int o = 0; o < OO; ++o) {
        float v = (o < 16) ? a0[o & 15] : (o < 32) ? a1[o & 15] : (o < 48) ? a2[o & 15] : a3[o & 15];
        v = v > 0.f ? v : 0.f;
        v += __shfl_down(v, 32);
        v += __shfl_down(v, 16);
        v += __shfl_down(v, 8);
        v += __shfl_down(v, 4);
        v += __shfl_down(v, 2);
        v += __shfl_down(v, 1);
        if (lane == 0) red[wv][o] = v;
    }
    __syncthreads();
    if (threadIdx.x < OO) {
        int o = threadIdx.x;
        partial[(size_t)(b * PIX_BLOCKS + pb) * OO + o] =
            red[0][o] + red[1][o] + red[2][o] + red[3][o];
    }
}

// ---------------- attention finish ----------------
__global__ void attn_finish_kernel(const float* __restrict__ partial,
                                   const float* __restrict__ fc_w, const float* __restrict__ fc_b,
                                   const float* __restrict__ fcs_w0, const float* __restrict__ fcs_b0,
                                   const float* __restrict__ fcs_w1, const float* __restrict__ fcs_b1,
                                   const float* __restrict__ fcs_w2, const float* __restrict__ fcs_b2,
                                   float* __restrict__ atts) {
    int b = blockIdx.x;
    __shared__ float attm[OO];
    __shared__ float fcv[32];
    int tid = threadIdx.x;
    if (tid < OO) {
        float s = 0.f;
        for (int blk = 0; blk < PIX_BLOCKS; ++blk)
            s += partial[(size_t)(b * PIX_BLOCKS + blk) * OO + tid];
        attm[tid] = s / (float)HWP;
    }
    __syncthreads();
    if (tid < 32) {
        float s = fc_b[tid];
        for (int o = 0; o < OO; ++o) s += fc_w[tid * OO + o] * attm[o];
        fcv[tid] = s > 0.f ? s : 0.f;
    }
    __syncthreads();
    if (tid < OO) {
        {
            float s = fcs_b0[tid];
            for (int j = 0; j < 32; ++j) s += fcs_w0[tid * 32 + j] * fcv[j];
            atts[b * 192 + 0 * OO + tid] = s;
        }
        {
            float s = fcs_b1[tid];
            for (int j = 0; j < 32; ++j) s += fcs_w1[tid * 32 + j] * fcv[j];
            atts[b * 192 + 1 * OO + tid] = s;
        }
        {
            float s = fcs_b2[tid];
            for (int j = 0; j < 32; ++j) s += fcs_w2[tid * 32 + j] * fcv[j];
            atts[b * 192 + 2 * OO + tid] = s;
        }
    }
}

// ---------------- final: scale + 1x1 conv + relu ----------------
__global__ __launch_bounds__(256)
void final_kernel(const float* __restrict__ outbuf, const float* __restrict__ atts,
                  const float* __restrict__ conv_wt, const float* __restrict__ conv_b,
                  float* __restrict__ out) {
    int blk = blockIdx.x;
    int b = blk / PIX_BLOCKS;
    int p = (blk % PIX_BLOCKS) * 256 + threadIdx.x;
    const float* ob = outbuf + (size_t)(b * 192) * HWP + p;
    const float* at = atts + b * 192;
    f32x16 a0, a1, a2, a3;
#pragma unroll
    for (int j = 0; j < 16; ++j) {
        a0[j] = conv_b[j]; a1[j] = conv_b[16 + j]; a2[j] = conv_b[32 + j]; a3[j] = conv_b[48 + j];
    }
    for (int c = 0; c < 192; ++c) {
        float v = ob[(size_t)c * HWP] * at[c];
        const float* wt = conv_wt + c * OO;
#pragma unroll
        for (int j = 0; j < 16; ++j) a0[j] += v * wt[j];
#pragma unroll
        for (int j = 0; j < 16; ++j) a1[j] += v * wt[16 + j];
#pragma unroll
        for (int j = 0; j < 16; ++j) a2[j] += v * wt[32 + j];
#pragma unroll
        for (int j = 0; j < 16; ++j) a3[j] += v * wt[48 + j];
    }
    float* op = out + (size_t)(b * OO) * HWP + p;
#pragma unroll
    for (int j = 0; j < 16; ++j) op[(size_t)j * HWP] = a0[j] > 0.f ? a0[j] : 0.f;
#pragma unroll
    for (int j = 0; j < 16; ++j) op[(size_t)(16 + j) * HWP] = a1[j] > 0.f ? a1[j] : 0.f;
#pragma unroll
    for (int j = 0; j < 16; ++j) op[(size_t)(32 + j) * HWP] = a2[j] > 0.f ? a2[j] : 0.f;
#pragma unroll
    for (int j = 0; j < 16; ++j) op[(size_t)(48 + j) * HWP] = a3[j] > 0.f ? a3[j] : 0.f;
}

extern "C" void kernel_launch(void* const* d_in, const int* in_sizes, int n_in,
                              void* d_out, int out_size, void* d_ws, size_t ws_size,
                              hipStream_t stream) {
    const float* fea    = (const float*)d_in[0];
    const float* inputs = (const float*)d_in[1];
    const float* dw_w[3]  = {(const float*)d_in[2],  (const float*)d_in[8],  (const float*)d_in[14]};
    const float* dw_b[3]  = {(const float*)d_in[3],  (const float*)d_in[9],  (const float*)d_in[15]};
    const float* pw_w[3]  = {(const float*)d_in[4],  (const float*)d_in[10], (const float*)d_in[16]};
    const float* pw_b[3]  = {(const float*)d_in[5],  (const float*)d_in[11], (const float*)d_in[17]};
    const float* dcn_w[3] = {(const float*)d_in[6],  (const float*)d_in[12], (const float*)d_in[18]};
    const float* dcn_b[3] = {(const float*)d_in[7],  (const float*)d_in[13], (const float*)d_in[19]};
    const float* attn_w = (const float*)d_in[20];
    const float* attn_b = (const float*)d_in[21];
    const float* fc_w   = (const float*)d_in[22];
    const float* fc_b   = (const float*)d_in[23];
    const float* fcs_w[3] = {(const float*)d_in[24], (const float*)d_in[26], (const float*)d_in[28]};
    const float* fcs_b[3] = {(const float*)d_in[25], (const float*)d_in[27], (const float*)d_in[29]};
    const float* conv_w = (const float*)d_in[30];
    const float* conv_b = (const float*)d_in[31];
    float* out = (float*)d_out;

    // workspace carve (floats): outbuf + om(chunk) + smalls.
    const size_t F_OUTBUF = (size_t)BB * 3 * OO * HWP;   // 28,311,552
    const size_t F_SMALL  = 36864 + 768 + 512 + 4096 + 11264 + 12288 + 12288; // 78,080
    float* W = (float*)d_ws;
    float* outbuf = W;            W += F_OUTBUF;
    float* om = W;                // 3*T*NTOT floats
    // tap chunk size from available ws (T=40 -> 184.3 MB total; proven ws >= 189.6 MB)
    size_t avail = ws_size / 4 - F_OUTBUF - F_SMALL;
    int T = (int)(avail / (3 * (size_t)NTOT));
    if (T > 40) T = 40;
    if (T < 1) T = 1;
    float* S = om + (size_t)3 * T * NTOT;
    float* partial = S;           S += 36864;
    float* atts = S;              S += 768;
    float* dcn_wt0 = S;           S += 512;
    float* dcn_wt1 = S;           S += 4096;
    float* dcn_wt2 = S;           S += 11264;
    float* attn_wt = S;           S += 12288;
    float* conv_wt = S;           S += 12288;
    float* dwscr = out;           // d_out as dw-plane scratch (exactly B*64*HWP floats);
                                  // dead before final_kernel rewrites d_out.

    // weight transposes
    transpose_kernel<<<(192 * 64 + 255) / 256, 256, 0, stream>>>(attn_w, attn_wt, 64, 192);
    transpose_kernel<<<(192 * 64 + 255) / 256, 256, 0, stream>>>(conv_w, conv_wt, 64, 192);
    transpose_kernel<<<(7 * 64 + 255) / 256, 256, 0, stream>>>(dcn_w[0], dcn_wt0, 64, 7);
    transpose_kernel<<<(63 * 64 + 255) / 256, 256, 0, stream>>>(dcn_w[1], dcn_wt1, 64, 63);
    transpose_kernel<<<(175 * 64 + 255) / 256, 256, 0, stream>>>(dcn_w[2], dcn_wt2, 64, 175);

    const int dw_grid = (BB * CF * HWP) / 256;   // 36864
    const int pix_grid = BB * PIX_BLOCKS;        // 576
    const int samp_grid = NTOT / 256;            // 576
    const int ntiles = NTOT / 128;               // 1152

    // ---- k=5 branch: dw -> chunked {pw GEMM -> sample/accumulate} ----
    dw_kernel<5><<<dw_grid, 256, 0, stream>>>(fea, dw_w[2], dw_b[2], dwscr);
    {
        const int TT = 175;
        for (int t0 = 0; t0 < TT; t0 += T) {
            int t1 = (t0 + T < TT) ? (t0 + T) : TT;
            int Tc = t1 - t0, M = 3 * Tc;
            int mt = (M + 63) / 64;
            pw_gemm_kernel<<<mt * ntiles, 256, 0, stream>>>(pw_w[2], pw_b[2], dwscr, om,
                                                            2 * t0, 2 * Tc, 2 * TT + t0, M);
            int flags = (t0 == 0 ? 1 : 0) | (t1 == TT ? 2 : 0);
            dcn_sample_kernel<5><<<samp_grid, 256, 0, stream>>>(om, inputs, dcn_wt2, dcn_b[2],
                                                                outbuf, 2, t0, t1, flags);
        }
    }
    // ---- k=3 branch ----
    dw_kernel<3><<<dw_grid, 256, 0, stream>>>(fea, dw_w[1], dw_b[1], dwscr);
    {
        const int TT = 63;
        for (int t0 = 0; t0 < TT; t0 += T) {
            int t1 = (t0 + T < TT) ? (t0 + T) : TT;
            int Tc = t1 - t0, M = 3 * Tc;
            int mt = (M + 63) / 64;
            pw_gemm_kernel<<<mt * ntiles, 256, 0, stream>>>(pw_w[1], pw_b[1], dwscr, om,
                                                            2 * t0, 2 * Tc, 2 * TT + t0, M);
            int flags = (t0 == 0 ? 1 : 0) | (t1 == TT ? 2 : 0);
            dcn_sample_kernel<3><<<samp_grid, 256, 0, stream>>>(om, inputs, dcn_wt1, dcn_b[1],
                                                                outbuf, 1, t0, t1, flags);
        }
    }
    // ---- k=1 branch (fused, tiny) ----
    branch_k1_kernel<<<pix_grid, 256, 0, stream>>>(fea, dw_w[0], dw_b[0], pw_w[0], pw_b[0],
                                                   inputs, dcn_wt0, dcn_b[0], outbuf);

    // ---- attention + final ----
    attn_sum_kernel<<<pix_grid, 256, 0, stream>>>(outbuf, attn_wt, attn_b, partial);
    attn_finish_kernel<<<BB, 64, 0, stream>>>(partial, fc_w, fc_b,
                                              fcs_w[0], fcs_b[0], fcs_w[1], fcs_b[1],
                                              fcs_w[2], fcs_b[2], atts);
    final_kernel<<<pix_grid, 256, 0, stream>>>(outbuf, atts, conv_wt, conv_b, out);
}

// Round 8
// 851.691 us; speedup vs baseline: 2.2050x; 1.1844x over previous
//
#include <hip/hip_runtime.h>
#include <math.h>

#define HH 192
#define WW 192
#define HWP (192*192)
#define BB 4
#define CF 64
#define NC 7
#define OO 64
#define NTOT (BB*HWP)          // 147456
#define PIX_BLOCKS (HWP/256)   // 144

typedef float f32x16 __attribute__((ext_vector_type(16)));
typedef float f32x4  __attribute__((ext_vector_type(4)));

// ---------------- vectorized depthwise conv: 4 outputs/thread -------------
// Round-7 lesson: scalar dw_kernel was issue-bound (25 VMEM/output, 11% of
// achievable HBM). 3 aligned float4 loads per row cover the 8-float window
// for 4 outputs; taps are wave-uniform -> scalar weight loads.
template<int k>
__global__ __launch_bounds__(256)
void dwv_kernel(const float* __restrict__ fea, const float* __restrict__ w,
                const float* __restrict__ bias, float* __restrict__ out) {
    constexpr int pad = k / 2;
    int idx = blockIdx.x * 256 + threadIdx.x;      // over B*CF*HH*48
    int xq = idx % 48;
    int x0 = xq * 4;
    int hpos = (idx / 48) % HH;
    int plane = idx / (48 * HH);                   // uniform per block (9216 %% 256 == 0)
    int c = plane % CF;
    const float* f = fea + (size_t)plane * HWP;

    float wk[k * k];
#pragma unroll
    for (int i = 0; i < k * k; ++i) wk[i] = w[c * k * k + i];

    float acc0 = 0.f, acc1 = 0.f, acc2 = 0.f, acc3 = 0.f;
#pragma unroll
    for (int dy = 0; dy < k; ++dy) {
        int y = hpos + dy - pad;
        if (y < 0 || y >= HH) continue;
        const float* row = f + y * WW;
        float4 q0 = (x0 >= 4) ? *(const float4*)(row + x0 - 4) : make_float4(0.f, 0.f, 0.f, 0.f);
        float4 q1 = *(const float4*)(row + x0);
        float4 q2 = (x0 + 4 < WW) ? *(const float4*)(row + x0 + 4) : make_float4(0.f, 0.f, 0.f, 0.f);
        float wnd[8] = {q0.z, q0.w, q1.x, q1.y, q1.z, q1.w, q2.x, q2.y};
#pragma unroll
        for (int dx = 0; dx < k; ++dx) {
            float wt = wk[dy * k + dx];
            // output i reads wnd[i + dx + 2 - pad]
            acc0 += wnd[0 + dx + 2 - pad] * wt;
            acc1 += wnd[1 + dx + 2 - pad] * wt;
            acc2 += wnd[2 + dx + 2 - pad] * wt;
            acc3 += wnd[3 + dx + 2 - pad] * wt;
        }
    }
    float b = bias[c];
    float4 o = make_float4(acc0 + b, acc1 + b, acc2 + b, acc3 + b);
    *(float4*)(out + (size_t)plane * HWP + hpos * WW + x0) = o;
}

// ---------------- generic small transpose ----------------
__global__ void transpose_kernel(const float* __restrict__ in, float* __restrict__ out,
                                 int rows, int cols) {
    int idx = blockIdx.x * 256 + threadIdx.x;
    if (idx >= rows * cols) return;
    int r = idx / cols, c = idx % cols;
    out[c * rows + r] = in[idx];
}

// ---------------- pw GEMM: om[m][NTOT] = pw_w[src(m)][:] @ dw + pw_b -------
__global__ __launch_bounds__(256)
void pw_gemm_kernel(const float* __restrict__ pw_w, const float* __restrict__ pw_b,
                    const float* __restrict__ dw, float* __restrict__ om,
                    int src0, int n_yx, int src1, int M) {
    __shared__ float As[64][68];    // [k][m], padded
    __shared__ float Bs[64][132];   // [k][n], padded
    const int ntiles = NTOT / 128;
    int ntile = blockIdx.x % ntiles;
    int mtile = blockIdx.x / ntiles;
    int nb0 = ntile * 128;
    int mb0 = mtile * 64;
    int tid = threadIdx.x;

    {
        int m = tid & 63;
        int kq = tid >> 6;
        int gm = mb0 + m;
        int srow = (gm < M) ? ((gm < n_yx) ? (src0 + gm) : (src1 + (gm - n_yx))) : src0;
        const float* ap = pw_w + (size_t)srow * CF;
#pragma unroll
        for (int i = 0; i < 4; ++i) {
            int k0 = (kq * 4 + i) * 4;
            float4 v = *(const float4*)(ap + k0);
            As[k0 + 0][m] = v.x; As[k0 + 1][m] = v.y;
            As[k0 + 2][m] = v.z; As[k0 + 3][m] = v.w;
        }
    }
    {
        int b = nb0 / HWP;
        int p0 = nb0 % HWP;
        const float* bp = dw + (size_t)b * CF * HWP + p0;
#pragma unroll
        for (int i = 0; i < 8; ++i) {
            int idx = tid + i * 256;
            int kk = idx >> 5;
            int f4 = idx & 31;
            float4 v = *(const float4*)(bp + (size_t)kk * HWP + f4 * 4);
            *(float4*)&Bs[kk][f4 * 4] = v;
        }
    }
    __syncthreads();

    int tm = (tid & 15) * 4;
    int tn = (tid >> 4) * 8;
    f32x4 aA0 = 0.f, aA1 = 0.f, aB0 = 0.f, aB1 = 0.f;
    f32x4 aC0 = 0.f, aC1 = 0.f, aD0 = 0.f, aD1 = 0.f;
#pragma unroll 8
    for (int kk = 0; kk < 64; ++kk) {
        f32x4 a  = *(const f32x4*)&As[kk][tm];
        f32x4 b0 = *(const f32x4*)&Bs[kk][tn];
        f32x4 b1 = *(const f32x4*)&Bs[kk][tn + 4];
#pragma unroll
        for (int j = 0; j < 4; ++j) {
            aA0[j] += a[0] * b0[j];  aA1[j] += a[0] * b1[j];
            aB0[j] += a[1] * b0[j];  aB1[j] += a[1] * b1[j];
            aC0[j] += a[2] * b0[j];  aC1[j] += a[2] * b1[j];
            aD0[j] += a[3] * b0[j];  aD1[j] += a[3] * b1[j];
        }
    }
    {
        int gm = mb0 + tm;
        float* dst = om + (size_t)gm * NTOT + nb0 + tn;
        if (gm < M) {
            float bi = pw_b[(gm < n_yx) ? (src0 + gm) : (src1 + gm - n_yx)];
#pragma unroll
            for (int j = 0; j < 4; ++j) { dst[j] = aA0[j] + bi; dst[4 + j] = aA1[j] + bi; }
        }
        gm++; dst += NTOT;
        if (gm < M) {
            float bi = pw_b[(gm < n_yx) ? (src0 + gm) : (src1 + gm - n_yx)];
#pragma unroll
            for (int j = 0; j < 4; ++j) { dst[j] = aB0[j] + bi; dst[4 + j] = aB1[j] + bi; }
        }
        gm++; dst += NTOT;
        if (gm < M) {
            float bi = pw_b[(gm < n_yx) ? (src0 + gm) : (src1 + gm - n_yx)];
#pragma unroll
            for (int j = 0; j < 4; ++j) { dst[j] = aC0[j] + bi; dst[4 + j] = aC1[j] + bi; }
        }
        gm++; dst += NTOT;
        if (gm < M) {
            float bi = pw_b[(gm < n_yx) ? (src0 + gm) : (src1 + gm - n_yx)];
#pragma unroll
            for (int j = 0; j < 4; ++j) { dst[j] = aD0[j] + bi; dst[4 + j] = aD1[j] + bi; }
        }
    }
}

// ---------------- deformable sampling + dcn accumulation (tap chunk) ------
template<int k>
__global__ __launch_bounds__(256)
void dcn_sample_kernel(const float* __restrict__ om,
                       const float* __restrict__ inputs,
                       const float* __restrict__ dcn_wt,   // [7K][64]
                       const float* __restrict__ dcn_b,
                       float* __restrict__ outbuf, int t_slot,
                       int t0, int t1, int flags) {
    constexpr int K = k * k;
    constexpr int pad = k / 2;
    int n = blockIdx.x * 256 + threadIdx.x;
    int b = n / HWP, p = n % HWP;
    int h = p / WW, wq = p % WW;
    const int T = t1 - t0;
    const float* inb = inputs + (size_t)b * NC * HWP;
    float* op = outbuf + (size_t)((b * 3 + t_slot) * OO) * HWP + p;

    f32x16 acc0, acc1, acc2, acc3;
    if (flags & 1) {
#pragma unroll
        for (int j = 0; j < 16; ++j) { acc0[j] = 0.f; acc1[j] = 0.f; acc2[j] = 0.f; acc3[j] = 0.f; }
    } else {
#pragma unroll
        for (int j = 0; j < 16; ++j) acc0[j] = op[(size_t)j * HWP];
#pragma unroll
        for (int j = 0; j < 16; ++j) acc1[j] = op[(size_t)(16 + j) * HWP];
#pragma unroll
        for (int j = 0; j < 16; ++j) acc2[j] = op[(size_t)(32 + j) * HWP];
#pragma unroll
        for (int j = 0; j < 16; ++j) acc3[j] = op[(size_t)(48 + j) * HWP];
    }

    for (int i = 0; i < T; ++i) {
        int r = t0 + i;
        float oy = om[(size_t)(2 * i) * NTOT + n];
        float ox = om[(size_t)(2 * i + 1) * NTOT + n];
        float mr = om[(size_t)(2 * T + i) * NTOT + n];
        int c = r / K;
        int kk = r - c * K;
        int ky = kk / k, kx = kk - ky * k;
        const float* inc_ = inb + (size_t)c * HWP;
        float m = 1.f / (1.f + __expf(-mr));
        float py = oy + (float)(ky + h - pad);
        float px = ox + (float)(kx + wq - pad);
        float y0 = floorf(py), x0 = floorf(px);
        float wyf = py - y0, wxf = px - x0;
        int iy0 = (int)y0, ix0 = (int)x0;
        bool y0v = (iy0 >= 0) && (iy0 < HH);
        bool y1v = (iy0 + 1 >= 0) && (iy0 + 1 < HH);
        bool x0v = (ix0 >= 0) && (ix0 < WW);
        bool x1v = (ix0 + 1 >= 0) && (ix0 + 1 < WW);
        int yc0 = min(max(iy0, 0), HH - 1), yc1 = min(max(iy0 + 1, 0), HH - 1);
        int xc0 = min(max(ix0, 0), WW - 1), xc1 = min(max(ix0 + 1, 0), WW - 1);
        float v00 = 0.f, v01 = 0.f, v10 = 0.f, v11 = 0.f;
        if (y0v) {
            if (x0v) v00 = inc_[yc0 * WW + xc0];
            if (x1v) v01 = inc_[yc0 * WW + xc1];
        }
        if (y1v) {
            if (x0v) v10 = inc_[yc1 * WW + xc0];
            if (x1v) v11 = inc_[yc1 * WW + xc1];
        }
        float s = (v00 * (1.f - wyf) * (1.f - wxf) + v01 * (1.f - wyf) * wxf +
                   v10 * wyf * (1.f - wxf) + v11 * wyf * wxf) * m;
        const float* dt = dcn_wt + (size_t)r * OO;
#pragma unroll
        for (int j = 0; j < 16; ++j) acc0[j] += s * dt[j];
#pragma unroll
        for (int j = 0; j < 16; ++j) acc1[j] += s * dt[16 + j];
#pragma unroll
        for (int j = 0; j < 16; ++j) acc2[j] += s * dt[32 + j];
#pragma unroll
        for (int j = 0; j < 16; ++j) acc3[j] += s * dt[48 + j];
    }

    if (flags & 2) {
#pragma unroll
        for (int j = 0; j < 16; ++j) { float v = acc0[j] + dcn_b[j];      op[(size_t)j * HWP] = v > 0.f ? v : 0.f; }
#pragma unroll
        for (int j = 0; j < 16; ++j) { float v = acc1[j] + dcn_b[16 + j]; op[(size_t)(16 + j) * HWP] = v > 0.f ? v : 0.f; }
#pragma unroll
        for (int j = 0; j < 16; ++j) { float v = acc2[j] + dcn_b[32 + j]; op[(size_t)(32 + j) * HWP] = v > 0.f ? v : 0.f; }
#pragma unroll
        for (int j = 0; j < 16; ++j) { float v = acc3[j] + dcn_b[48 + j]; op[(size_t)(48 + j) * HWP] = v > 0.f ? v : 0.f; }
    } else {
#pragma unroll
        for (int j = 0; j < 16; ++j) op[(size_t)j * HWP] = acc0[j];
#pragma unroll
        for (int j = 0; j < 16; ++j) op[(size_t)(16 + j) * HWP] = acc1[j];
#pragma unroll
        for (int j = 0; j < 16; ++j) op[(size_t)(32 + j) * HWP] = acc2[j];
#pragma unroll
        for (int j = 0; j < 16; ++j) op[(size_t)(48 + j) * HWP] = acc3[j];
    }
}

// ---------------- k=1 branch: fused elementwise dw + 7-tap deform ---------
__global__ __launch_bounds__(256)
void branch_k1_kernel(const float* __restrict__ fea,
                      const float* __restrict__ dw_w0, const float* __restrict__ dw_b0,
                      const float* __restrict__ pw_w, const float* __restrict__ pw_b,
                      const float* __restrict__ inputs,
                      const float* __restrict__ dcn_wt, const float* __restrict__ dcn_b,
                      float* __restrict__ outbuf) {
    __shared__ float lw[21 * 64];
    for (int i = threadIdx.x; i < 21 * 16; i += 256)
        ((float4*)lw)[i] = ((const float4*)pw_w)[i];
    __syncthreads();
    int gid = blockIdx.x;
    int b = gid / PIX_BLOCKS;
    int p = (gid % PIX_BLOCKS) * 256 + threadIdx.x;
    int h = p / WW, wq = p % WW;
    const float* inb = inputs + (size_t)b * NC * HWP;

    f32x16 dwv0, dwv1, dwv2, dwv3;
    {
        const float* fp = fea + (size_t)(b * CF) * HWP + p;
#pragma unroll
        for (int j = 0; j < 16; ++j) dwv0[j] = fp[(size_t)j * HWP] * dw_w0[j] + dw_b0[j];
#pragma unroll
        for (int j = 0; j < 16; ++j) dwv1[j] = fp[(size_t)(16 + j) * HWP] * dw_w0[16 + j] + dw_b0[16 + j];
#pragma unroll
        for (int j = 0; j < 16; ++j) dwv2[j] = fp[(size_t)(32 + j) * HWP] * dw_w0[32 + j] + dw_b0[32 + j];
#pragma unroll
        for (int j = 0; j < 16; ++j) dwv3[j] = fp[(size_t)(48 + j) * HWP] * dw_w0[48 + j] + dw_b0[48 + j];
    }
    f32x16 acc0, acc1, acc2, acc3;
#pragma unroll
    for (int j = 0; j < 16; ++j) { acc0[j] = 0.f; acc1[j] = 0.f; acc2[j] = 0.f; acc3[j] = 0.f; }

    for (int r = 0; r < NC; ++r) {
        const float* wy = lw + (2 * r) * 64;
        const float* wx = wy + 64;
        const float* wm = lw + (14 + r) * 64;
        const float* inc_ = inb + (size_t)r * HWP;
        float oy = pw_b[2 * r], ox = pw_b[2 * r + 1], om = pw_b[14 + r];
#pragma unroll
        for (int j = 0; j < 16; ++j) { oy += wy[j] * dwv0[j];      ox += wx[j] * dwv0[j];      om += wm[j] * dwv0[j]; }
#pragma unroll
        for (int j = 0; j < 16; ++j) { oy += wy[16 + j] * dwv1[j]; ox += wx[16 + j] * dwv1[j]; om += wm[16 + j] * dwv1[j]; }
#pragma unroll
        for (int j = 0; j < 16; ++j) { oy += wy[32 + j] * dwv2[j]; ox += wx[32 + j] * dwv2[j]; om += wm[32 + j] * dwv2[j]; }
#pragma unroll
        for (int j = 0; j < 16; ++j) { oy += wy[48 + j] * dwv3[j]; ox += wx[48 + j] * dwv3[j]; om += wm[48 + j] * dwv3[j]; }
        float m = 1.f / (1.f + __expf(-om));
        float py = oy + (float)h;
        float px = ox + (float)wq;
        float y0 = floorf(py), x0 = floorf(px);
        float wyf = py - y0, wxf = px - x0;
        int iy0 = (int)y0, ix0 = (int)x0;
        bool y0v = (iy0 >= 0) && (iy0 < HH);
        bool y1v = (iy0 + 1 >= 0) && (iy0 + 1 < HH);
        bool x0v = (ix0 >= 0) && (ix0 < WW);
        bool x1v = (ix0 + 1 >= 0) && (ix0 + 1 < WW);
        int yc0 = min(max(iy0, 0), HH - 1), yc1 = min(max(iy0 + 1, 0), HH - 1);
        int xc0 = min(max(ix0, 0), WW - 1), xc1 = min(max(ix0 + 1, 0), WW - 1);
        float v00 = 0.f, v01 = 0.f, v10 = 0.f, v11 = 0.f;
        if (y0v) {
            if (x0v) v00 = inc_[yc0 * WW + xc0];
            if (x1v) v01 = inc_[yc0 * WW + xc1];
        }
        if (y1v) {
            if (x0v) v10 = inc_[yc1 * WW + xc0];
            if (x1v) v11 = inc_[yc1 * WW + xc1];
        }
        float s = (v00 * (1.f - wyf) * (1.f - wxf) + v01 * (1.f - wyf) * wxf +
                   v10 * wyf * (1.f - wxf) + v11 * wyf * wxf) * m;
        const float* dt = dcn_wt + (size_t)r * OO;
#pragma unroll
        for (int j = 0; j < 16; ++j) acc0[j] += s * dt[j];
#pragma unroll
        for (int j = 0; j < 16; ++j) acc1[j] += s * dt[16 + j];
#pragma unroll
        for (int j = 0; j < 16; ++j) acc2[j] += s * dt[32 + j];
#pragma unroll
        for (int j = 0; j < 16; ++j) acc3[j] += s * dt[48 + j];
    }
    float* op = outbuf + (size_t)(b * 3 * OO) * HWP + p;
#pragma unroll
    for (int j = 0; j < 16; ++j) { float v = acc0[j] + dcn_b[j];      op[(size_t)j * HWP] = v > 0.f ? v : 0.f; }
#pragma unroll
    for (int j = 0; j < 16; ++j) { float v = acc1[j] + dcn_b[16 + j]; op[(size_t)(16 + j) * HWP] = v > 0.f ? v : 0.f; }
#pragma unroll
    for (int j = 0; j < 16; ++j) { float v = acc2[j] + dcn_b[32 + j]; op[(size_t)(32 + j) * HWP] = v > 0.f ? v : 0.f; }
#pragma unroll
    for (int j = 0; j < 16; ++j) { float v = acc3[j] + dcn_b[48 + j]; op[(size_t)(48 + j) * HWP] = v > 0.f ? v : 0.f; }
}

// ---------------- attention: per-block partial sums of relu(attn pw) ------
__global__ __launch_bounds__(256)
void attn_sum_kernel(const float* __restrict__ outbuf, const float* __restrict__ attn_wt,
                     const float* __restrict__ attn_b, float* __restrict__ partial) {
    int blk = blockIdx.x;
    int b = blk / PIX_BLOCKS;
    int pb = blk % PIX_BLOCKS;
    int p = pb * 256 + threadIdx.x;
    const float* ob = outbuf + (size_t)(b * 192) * HWP + p;
    f32x16 a0, a1, a2, a3;
#pragma unroll
    for (int j = 0; j < 16; ++j) {
        a0[j] = attn_b[j]; a1[j] = attn_b[16 + j]; a2[j] = attn_b[32 + j]; a3[j] = attn_b[48 + j];
    }
    for (int c = 0; c < 192; ++c) {
        float v = ob[(size_t)c * HWP];
        const float* wt = attn_wt + c * OO;
#pragma unroll
        for (int j = 0; j < 16; ++j) a0[j] += v * wt[j];
#pragma unroll
        for (int j = 0; j < 16; ++j) a1[j] += v * wt[16 + j];
#pragma unroll
        for (int j = 0; j < 16; ++j) a2[j] += v * wt[32 + j];
#pragma unroll
        for (int j = 0; j < 16; ++j) a3[j] += v * wt[48 + j];
    }
    __shared__ float red[4][OO];
    int lane = threadIdx.x & 63, wv = threadIdx.x >> 6;
#pragma unroll
    for (int o = 0; o < OO; ++o) {
        float v = (o < 16) ? a0[o & 15] : (o < 32) ? a1[o & 15] : (o < 48) ? a2[o & 15] : a3[o & 15];
        v = v > 0.f ? v : 0.f;
        v += __shfl_down(v, 32);
        v += __shfl_down(v, 16);
        v += __shfl_down(v, 8);
        v += __shfl_down(v, 4);
        v += __shfl_down(v, 2);
        v += __shfl_down(v, 1);
        if (lane == 0) red[wv][o] = v;
    }
    __syncthreads();
    if (threadIdx.x < OO) {
        int o = threadIdx.x;
        partial[(size_t)(b * PIX_BLOCKS + pb) * OO + o] =
            red[0][o] + red[1][o] + red[2][o] + red[3][o];
    }
}

// ---------------- attention finish ----------------
__global__ void attn_finish_kernel(const float* __restrict__ partial,
                                   const float* __restrict__ fc_w, const float* __restrict__ fc_b,
                                   const float* __restrict__ fcs_w0, const float* __restrict__ fcs_b0,
                                   const float* __restrict__ fcs_w1, const float* __restrict__ fcs_b1,
                                   const float* __restrict__ fcs_w2, const float* __restrict__ fcs_b2,
                                   float* __restrict__ atts) {
    int b = blockIdx.x;
    __shared__ float attm[OO];
    __shared__ float fcv[32];
    int tid = threadIdx.x;
    if (tid < OO) {
        float s = 0.f;
        for (int blk = 0; blk < PIX_BLOCKS; ++blk)
            s += partial[(size_t)(b * PIX_BLOCKS + blk) * OO + tid];
        attm[tid] = s / (float)HWP;
    }
    __syncthreads();
    if (tid < 32) {
        float s = fc_b[tid];
        for (int o = 0; o < OO; ++o) s += fc_w[tid * OO + o] * attm[o];
        fcv[tid] = s > 0.f ? s : 0.f;
    }
    __syncthreads();
    if (tid < OO) {
        {
            float s = fcs_b0[tid];
            for (int j = 0; j < 32; ++j) s += fcs_w0[tid * 32 + j] * fcv[j];
            atts[b * 192 + 0 * OO + tid] = s;
        }
        {
            float s = fcs_b1[tid];
            for (int j = 0; j < 32; ++j) s += fcs_w1[tid * 32 + j] * fcv[j];
            atts[b * 192 + 1 * OO + tid] = s;
        }
        {
            float s = fcs_b2[tid];
            for (int j = 0; j < 32; ++j) s += fcs_w2[tid * 32 + j] * fcv[j];
            atts[b * 192 + 2 * OO + tid] = s;
        }
    }
}

// ---------------- final: scale + 1x1 conv + relu ----------------
__global__ __launch_bounds__(256)
void final_kernel(const float* __restrict__ outbuf, const float* __restrict__ atts,
                  const float* __restrict__ conv_wt, const float* __restrict__ conv_b,
                  float* __restrict__ out) {
    int blk = blockIdx.x;
    int b = blk / PIX_BLOCKS;
    int p = (blk % PIX_BLOCKS) * 256 + threadIdx.x;
    const float* ob = outbuf + (size_t)(b * 192) * HWP + p;
    const float* at = atts + b * 192;
    f32x16 a0, a1, a2, a3;
#pragma unroll
    for (int j = 0; j < 16; ++j) {
        a0[j] = conv_b[j]; a1[j] = conv_b[16 + j]; a2[j] = conv_b[32 + j]; a3[j] = conv_b[48 + j];
    }
    for (int c = 0; c < 192; ++c) {
        float v = ob[(size_t)c * HWP] * at[c];
        const float* wt = conv_wt + c * OO;
#pragma unroll
        for (int j = 0; j < 16; ++j) a0[j] += v * wt[j];
#pragma unroll
        for (int j = 0; j < 16; ++j) a1[j] += v * wt[16 + j];
#pragma unroll
        for (int j = 0; j < 16; ++j) a2[j] += v * wt[32 + j];
#pragma unroll
        for (int j = 0; j < 16; ++j) a3[j] += v * wt[48 + j];
    }
    float* op = out + (size_t)(b * OO) * HWP + p;
#pragma unroll
    for (int j = 0; j < 16; ++j) op[(size_t)j * HWP] = a0[j] > 0.f ? a0[j] : 0.f;
#pragma unroll
    for (int j = 0; j < 16; ++j) op[(size_t)(16 + j) * HWP] = a1[j] > 0.f ? a1[j] : 0.f;
#pragma unroll
    for (int j = 0; j < 16; ++j) op[(size_t)(32 + j) * HWP] = a2[j] > 0.f ? a2[j] : 0.f;
#pragma unroll
    for (int j = 0; j < 16; ++j) op[(size_t)(48 + j) * HWP] = a3[j] > 0.f ? a3[j] : 0.f;
}

extern "C" void kernel_launch(void* const* d_in, const int* in_sizes, int n_in,
                              void* d_out, int out_size, void* d_ws, size_t ws_size,
                              hipStream_t stream) {
    const float* fea    = (const float*)d_in[0];
    const float* inputs = (const float*)d_in[1];
    const float* dw_w[3]  = {(const float*)d_in[2],  (const float*)d_in[8],  (const float*)d_in[14]};
    const float* dw_b[3]  = {(const float*)d_in[3],  (const float*)d_in[9],  (const float*)d_in[15]};
    const float* pw_w[3]  = {(const float*)d_in[4],  (const float*)d_in[10], (const float*)d_in[16]};
    const float* pw_b[3]  = {(const float*)d_in[5],  (const float*)d_in[11], (const float*)d_in[17]};
    const float* dcn_w[3] = {(const float*)d_in[6],  (const float*)d_in[12], (const float*)d_in[18]};
    const float* dcn_b[3] = {(const float*)d_in[7],  (const float*)d_in[13], (const float*)d_in[19]};
    const float* attn_w = (const float*)d_in[20];
    const float* attn_b = (const float*)d_in[21];
    const float* fc_w   = (const float*)d_in[22];
    const float* fc_b   = (const float*)d_in[23];
    const float* fcs_w[3] = {(const float*)d_in[24], (const float*)d_in[26], (const float*)d_in[28]};
    const float* fcs_b[3] = {(const float*)d_in[25], (const float*)d_in[27], (const float*)d_in[29]};
    const float* conv_w = (const float*)d_in[30];
    const float* conv_b = (const float*)d_in[31];
    float* out = (float*)d_out;

    // workspace carve (floats): outbuf + om(chunk) + smalls.
    const size_t F_OUTBUF = (size_t)BB * 3 * OO * HWP;   // 28,311,552
    const size_t F_SMALL  = 36864 + 768 + 512 + 4096 + 11264 + 12288 + 12288;
    float* W = (float*)d_ws;
    float* outbuf = W;            W += F_OUTBUF;
    float* om = W;                // 3*T*NTOT floats
    size_t avail = (ws_size / 4 > F_OUTBUF + F_SMALL) ? (ws_size / 4 - F_OUTBUF - F_SMALL) : 0;
    int T = (int)(avail / (3 * (size_t)NTOT));
    if (T > 175) T = 175;        // one full k5 branch; runtime ws_size is the only cap
    if (T < 1) T = 1;
    float* S = om + (size_t)3 * T * NTOT;
    float* partial = S;           S += 36864;
    float* atts = S;              S += 768;
    float* dcn_wt0 = S;           S += 512;
    float* dcn_wt1 = S;           S += 4096;
    float* dcn_wt2 = S;           S += 11264;
    float* attn_wt = S;           S += 12288;
    float* conv_wt = S;           S += 12288;
    float* dwscr = out;           // d_out as dw-plane scratch; final_kernel rewrites d_out

    // weight transposes
    transpose_kernel<<<(192 * 64 + 255) / 256, 256, 0, stream>>>(attn_w, attn_wt, 64, 192);
    transpose_kernel<<<(192 * 64 + 255) / 256, 256, 0, stream>>>(conv_w, conv_wt, 64, 192);
    transpose_kernel<<<(7 * 64 + 255) / 256, 256, 0, stream>>>(dcn_w[0], dcn_wt0, 64, 7);
    transpose_kernel<<<(63 * 64 + 255) / 256, 256, 0, stream>>>(dcn_w[1], dcn_wt1, 64, 63);
    transpose_kernel<<<(175 * 64 + 255) / 256, 256, 0, stream>>>(dcn_w[2], dcn_wt2, 64, 175);

    const int dwv_grid = (BB * CF * HH * 48) / 256;   // 9216
    const int pix_grid = BB * PIX_BLOCKS;             // 576
    const int samp_grid = NTOT / 256;                 // 576
    const int ntiles = NTOT / 128;                    // 1152

    // ---- k=5 branch: dw -> chunked {pw GEMM -> sample/accumulate} ----
    dwv_kernel<5><<<dwv_grid, 256, 0, stream>>>(fea, dw_w[2], dw_b[2], dwscr);
    {
        const int TT = 175;
        for (int t0 = 0; t0 < TT; t0 += T) {
            int t1 = (t0 + T < TT) ? (t0 + T) : TT;
            int Tc = t1 - t0, M = 3 * Tc;
            int mt = (M + 63) / 64;
            pw_gemm_kernel<<<mt * ntiles, 256, 0, stream>>>(pw_w[2], pw_b[2], dwscr, om,
                                                            2 * t0, 2 * Tc, 2 * TT + t0, M);
            int flags = (t0 == 0 ? 1 : 0) | (t1 == TT ? 2 : 0);
            dcn_sample_kernel<5><<<samp_grid, 256, 0, stream>>>(om, inputs, dcn_wt2, dcn_b[2],
                                                                outbuf, 2, t0, t1, flags);
        }
    }
    // ---- k=3 branch ----
    dwv_kernel<3><<<dwv_grid, 256, 0, stream>>>(fea, dw_w[1], dw_b[1], dwscr);
    {
        const int TT = 63;
        for (int t0 = 0; t0 < TT; t0 += T) {
            int t1 = (t0 + T < TT) ? (t0 + T) : TT;
            int Tc = t1 - t0, M = 3 * Tc;
            int mt = (M + 63) / 64;
            pw_gemm_kernel<<<mt * ntiles, 256, 0, stream>>>(pw_w[1], pw_b[1], dwscr, om,
                                                            2 * t0, 2 * Tc, 2 * TT + t0, M);
            int flags = (t0 == 0 ? 1 : 0) | (t1 == TT ? 2 : 0);
            dcn_sample_kernel<3><<<samp_grid, 256, 0, stream>>>(om, inputs, dcn_wt1, dcn_b[1],
                                                                outbuf, 1, t0, t1, flags);
        }
    }
    // ---- k=1 branch (fused, tiny) ----
    branch_k1_kernel<<<pix_grid, 256, 0, stream>>>(fea, dw_w[0], dw_b[0], pw_w[0], pw_b[0],
                                                   inputs, dcn_wt0, dcn_b[0], outbuf);

    // ---- attention + final ----
    attn_sum_kernel<<<pix_grid, 256, 0, stream>>>(outbuf, attn_wt, attn_b, partial);
    attn_finish_kernel<<<BB, 64, 0, stream>>>(partial, fc_w, fc_b,
                                              fcs_w[0], fcs_b[0], fcs_w[1], fcs_b[1],
                                              fcs_w[2], fcs_b[2], atts);
    final_kernel<<<pix_grid, 256, 0, stream>>>(outbuf, atts, conv_wt, conv_b, out);
}

// Round 9
// 818.054 us; speedup vs baseline: 2.2957x; 1.0411x over previous
//
#include <hip/hip_runtime.h>
#include <math.h>

#define HH 192
#define WW 192
#define HWP (192*192)
#define BB 4
#define CF 64
#define NC 7
#define OO 64
#define NTOT (BB*HWP)          // 147456
#define PIX_BLOCKS (HWP/256)   // 144

typedef float f32x16 __attribute__((ext_vector_type(16)));
typedef float f32x4  __attribute__((ext_vector_type(4)));

// ---------------- vectorized depthwise conv: 4 outputs/thread -------------
template<int k>
__global__ __launch_bounds__(256)
void dwv_kernel(const float* __restrict__ fea, const float* __restrict__ w,
                const float* __restrict__ bias, float* __restrict__ out) {
    constexpr int pad = k / 2;
    int idx = blockIdx.x * 256 + threadIdx.x;      // over B*CF*HH*48
    int xq = idx % 48;
    int x0 = xq * 4;
    int hpos = (idx / 48) % HH;
    int plane = idx / (48 * HH);                   // uniform per block
    int c = plane % CF;
    const float* f = fea + (size_t)plane * HWP;

    float wk[k * k];
#pragma unroll
    for (int i = 0; i < k * k; ++i) wk[i] = w[c * k * k + i];

    float acc0 = 0.f, acc1 = 0.f, acc2 = 0.f, acc3 = 0.f;
#pragma unroll
    for (int dy = 0; dy < k; ++dy) {
        int y = hpos + dy - pad;
        if (y < 0 || y >= HH) continue;
        const float* row = f + y * WW;
        float4 q0 = (x0 >= 4) ? *(const float4*)(row + x0 - 4) : make_float4(0.f, 0.f, 0.f, 0.f);
        float4 q1 = *(const float4*)(row + x0);
        float4 q2 = (x0 + 4 < WW) ? *(const float4*)(row + x0 + 4) : make_float4(0.f, 0.f, 0.f, 0.f);
        float wnd[8] = {q0.z, q0.w, q1.x, q1.y, q1.z, q1.w, q2.x, q2.y};
#pragma unroll
        for (int dx = 0; dx < k; ++dx) {
            float wt = wk[dy * k + dx];
            acc0 += wnd[0 + dx + 2 - pad] * wt;
            acc1 += wnd[1 + dx + 2 - pad] * wt;
            acc2 += wnd[2 + dx + 2 - pad] * wt;
            acc3 += wnd[3 + dx + 2 - pad] * wt;
        }
    }
    float b = bias[c];
    float4 o = make_float4(acc0 + b, acc1 + b, acc2 + b, acc3 + b);
    *(float4*)(out + (size_t)plane * HWP + hpos * WW + x0) = o;
}

// ---------------- generic small transpose ----------------
__global__ void transpose_kernel(const float* __restrict__ in, float* __restrict__ out,
                                 int rows, int cols) {
    int idx = blockIdx.x * 256 + threadIdx.x;
    if (idx >= rows * cols) return;
    int r = idx / cols, c = idx % cols;
    out[c * rows + r] = in[idx];
}

// ---------------- pw GEMM: om[m][NTOT] = pw_w[src(m)][:] @ dw + pw_b -------
__global__ __launch_bounds__(256)
void pw_gemm_kernel(const float* __restrict__ pw_w, const float* __restrict__ pw_b,
                    const float* __restrict__ dw, float* __restrict__ om,
                    int src0, int n_yx, int src1, int M) {
    __shared__ float As[64][68];
    __shared__ float Bs[64][132];
    const int ntiles = NTOT / 128;
    int ntile = blockIdx.x % ntiles;
    int mtile = blockIdx.x / ntiles;
    int nb0 = ntile * 128;
    int mb0 = mtile * 64;
    int tid = threadIdx.x;

    {
        int m = tid & 63;
        int kq = tid >> 6;
        int gm = mb0 + m;
        int srow = (gm < M) ? ((gm < n_yx) ? (src0 + gm) : (src1 + (gm - n_yx))) : src0;
        const float* ap = pw_w + (size_t)srow * CF;
#pragma unroll
        for (int i = 0; i < 4; ++i) {
            int k0 = (kq * 4 + i) * 4;
            float4 v = *(const float4*)(ap + k0);
            As[k0 + 0][m] = v.x; As[k0 + 1][m] = v.y;
            As[k0 + 2][m] = v.z; As[k0 + 3][m] = v.w;
        }
    }
    {
        int b = nb0 / HWP;
        int p0 = nb0 % HWP;
        const float* bp = dw + (size_t)b * CF * HWP + p0;
#pragma unroll
        for (int i = 0; i < 8; ++i) {
            int idx = tid + i * 256;
            int kk = idx >> 5;
            int f4 = idx & 31;
            float4 v = *(const float4*)(bp + (size_t)kk * HWP + f4 * 4);
            *(float4*)&Bs[kk][f4 * 4] = v;
        }
    }
    __syncthreads();

    int tm = (tid & 15) * 4;
    int tn = (tid >> 4) * 8;
    f32x4 aA0 = 0.f, aA1 = 0.f, aB0 = 0.f, aB1 = 0.f;
    f32x4 aC0 = 0.f, aC1 = 0.f, aD0 = 0.f, aD1 = 0.f;
#pragma unroll 8
    for (int kk = 0; kk < 64; ++kk) {
        f32x4 a  = *(const f32x4*)&As[kk][tm];
        f32x4 b0 = *(const f32x4*)&Bs[kk][tn];
        f32x4 b1 = *(const f32x4*)&Bs[kk][tn + 4];
#pragma unroll
        for (int j = 0; j < 4; ++j) {
            aA0[j] += a[0] * b0[j];  aA1[j] += a[0] * b1[j];
            aB0[j] += a[1] * b0[j];  aB1[j] += a[1] * b1[j];
            aC0[j] += a[2] * b0[j];  aC1[j] += a[2] * b1[j];
            aD0[j] += a[3] * b0[j];  aD1[j] += a[3] * b1[j];
        }
    }
    {
        int gm = mb0 + tm;
        float* dst = om + (size_t)gm * NTOT + nb0 + tn;
        if (gm < M) {
            float bi = pw_b[(gm < n_yx) ? (src0 + gm) : (src1 + gm - n_yx)];
#pragma unroll
            for (int j = 0; j < 4; ++j) { dst[j] = aA0[j] + bi; dst[4 + j] = aA1[j] + bi; }
        }
        gm++; dst += NTOT;
        if (gm < M) {
            float bi = pw_b[(gm < n_yx) ? (src0 + gm) : (src1 + gm - n_yx)];
#pragma unroll
            for (int j = 0; j < 4; ++j) { dst[j] = aB0[j] + bi; dst[4 + j] = aB1[j] + bi; }
        }
        gm++; dst += NTOT;
        if (gm < M) {
            float bi = pw_b[(gm < n_yx) ? (src0 + gm) : (src1 + gm - n_yx)];
#pragma unroll
            for (int j = 0; j < 4; ++j) { dst[j] = aC0[j] + bi; dst[4 + j] = aC1[j] + bi; }
        }
        gm++; dst += NTOT;
        if (gm < M) {
            float bi = pw_b[(gm < n_yx) ? (src0 + gm) : (src1 + gm - n_yx)];
#pragma unroll
            for (int j = 0; j < 4; ++j) { dst[j] = aD0[j] + bi; dst[4 + j] = aD1[j] + bi; }
        }
    }
}

// ---------------- deformable sampling + dcn accumulation (tap chunk) ------
// Round-8 lesson: 576-block grid = 2.25 waves/SIMD -> latency-bound (23% occ,
// 29% VALU). Channel-split x2: each block computes 32 of the 64 outputs for
// its 256 pixels; waves double, sampling arithmetic duplicated (cheap), om +
// gather lines shared in L2 between the paired blocks.
template<int k>
__global__ __launch_bounds__(256)
void dcn_sample_kernel(const float* __restrict__ om,
                       const float* __restrict__ inputs,
                       const float* __restrict__ dcn_wt,   // [7K][64]
                       const float* __restrict__ dcn_b,
                       float* __restrict__ outbuf, int t_slot,
                       int t0, int t1, int flags) {
    constexpr int K = k * k;
    constexpr int pad = k / 2;
    int g = blockIdx.x & 1;                 // channel group: [32g, 32g+32)
    int nb = blockIdx.x >> 1;
    int n = nb * 256 + threadIdx.x;
    int b = n / HWP, p = n % HWP;
    int h = p / WW, wq = p % WW;
    const int T = t1 - t0;
    const float* inb = inputs + (size_t)b * NC * HWP;
    float* op = outbuf + ((size_t)((b * 3 + t_slot) * OO) + g * 32) * HWP + p;
    const float* db = dcn_b + g * 32;

    f32x16 acc0, acc1;
    if (flags & 1) {
#pragma unroll
        for (int j = 0; j < 16; ++j) { acc0[j] = 0.f; acc1[j] = 0.f; }
    } else {
#pragma unroll
        for (int j = 0; j < 16; ++j) acc0[j] = op[(size_t)j * HWP];
#pragma unroll
        for (int j = 0; j < 16; ++j) acc1[j] = op[(size_t)(16 + j) * HWP];
    }

    for (int i = 0; i < T; ++i) {
        int r = t0 + i;
        float oy = om[(size_t)(2 * i) * NTOT + n];
        float ox = om[(size_t)(2 * i + 1) * NTOT + n];
        float mr = om[(size_t)(2 * T + i) * NTOT + n];
        int c = r / K;
        int kk = r - c * K;
        int ky = kk / k, kx = kk - ky * k;
        const float* inc_ = inb + (size_t)c * HWP;
        float m = 1.f / (1.f + __expf(-mr));
        float py = oy + (float)(ky + h - pad);
        float px = ox + (float)(kx + wq - pad);
        float y0 = floorf(py), x0 = floorf(px);
        float wyf = py - y0, wxf = px - x0;
        int iy0 = (int)y0, ix0 = (int)x0;
        bool y0v = (iy0 >= 0) && (iy0 < HH);
        bool y1v = (iy0 + 1 >= 0) && (iy0 + 1 < HH);
        bool x0v = (ix0 >= 0) && (ix0 < WW);
        bool x1v = (ix0 + 1 >= 0) && (ix0 + 1 < WW);
        int yc0 = min(max(iy0, 0), HH - 1), yc1 = min(max(iy0 + 1, 0), HH - 1);
        int xc0 = min(max(ix0, 0), WW - 1), xc1 = min(max(ix0 + 1, 0), WW - 1);
        float v00 = 0.f, v01 = 0.f, v10 = 0.f, v11 = 0.f;
        if (y0v) {
            if (x0v) v00 = inc_[yc0 * WW + xc0];
            if (x1v) v01 = inc_[yc0 * WW + xc1];
        }
        if (y1v) {
            if (x0v) v10 = inc_[yc1 * WW + xc0];
            if (x1v) v11 = inc_[yc1 * WW + xc1];
        }
        float s = (v00 * (1.f - wyf) * (1.f - wxf) + v01 * (1.f - wyf) * wxf +
                   v10 * wyf * (1.f - wxf) + v11 * wyf * wxf) * m;
        const float* dt = dcn_wt + (size_t)r * OO + g * 32;
#pragma unroll
        for (int j = 0; j < 16; ++j) acc0[j] += s * dt[j];
#pragma unroll
        for (int j = 0; j < 16; ++j) acc1[j] += s * dt[16 + j];
    }

    if (flags & 2) {
#pragma unroll
        for (int j = 0; j < 16; ++j) { float v = acc0[j] + db[j];      op[(size_t)j * HWP] = v > 0.f ? v : 0.f; }
#pragma unroll
        for (int j = 0; j < 16; ++j) { float v = acc1[j] + db[16 + j]; op[(size_t)(16 + j) * HWP] = v > 0.f ? v : 0.f; }
    } else {
#pragma unroll
        for (int j = 0; j < 16; ++j) op[(size_t)j * HWP] = acc0[j];
#pragma unroll
        for (int j = 0; j < 16; ++j) op[(size_t)(16 + j) * HWP] = acc1[j];
    }
}

// ---------------- k=1 branch: fused elementwise dw + 7-tap deform ---------
__global__ __launch_bounds__(256)
void branch_k1_kernel(const float* __restrict__ fea,
                      const float* __restrict__ dw_w0, const float* __restrict__ dw_b0,
                      const float* __restrict__ pw_w, const float* __restrict__ pw_b,
                      const float* __restrict__ inputs,
                      const float* __restrict__ dcn_wt, const float* __restrict__ dcn_b,
                      float* __restrict__ outbuf) {
    __shared__ float lw[21 * 64];
    for (int i = threadIdx.x; i < 21 * 16; i += 256)
        ((float4*)lw)[i] = ((const float4*)pw_w)[i];
    __syncthreads();
    int gid = blockIdx.x;
    int b = gid / PIX_BLOCKS;
    int p = (gid % PIX_BLOCKS) * 256 + threadIdx.x;
    int h = p / WW, wq = p % WW;
    const float* inb = inputs + (size_t)b * NC * HWP;

    f32x16 dwv0, dwv1, dwv2, dwv3;
    {
        const float* fp = fea + (size_t)(b * CF) * HWP + p;
#pragma unroll
        for (int j = 0; j < 16; ++j) dwv0[j] = fp[(size_t)j * HWP] * dw_w0[j] + dw_b0[j];
#pragma unroll
        for (int j = 0; j < 16; ++j) dwv1[j] = fp[(size_t)(16 + j) * HWP] * dw_w0[16 + j] + dw_b0[16 + j];
#pragma unroll
        for (int j = 0; j < 16; ++j) dwv2[j] = fp[(size_t)(32 + j) * HWP] * dw_w0[32 + j] + dw_b0[32 + j];
#pragma unroll
        for (int j = 0; j < 16; ++j) dwv3[j] = fp[(size_t)(48 + j) * HWP] * dw_w0[48 + j] + dw_b0[48 + j];
    }
    f32x16 acc0, acc1, acc2, acc3;
#pragma unroll
    for (int j = 0; j < 16; ++j) { acc0[j] = 0.f; acc1[j] = 0.f; acc2[j] = 0.f; acc3[j] = 0.f; }

    for (int r = 0; r < NC; ++r) {
        const float* wy = lw + (2 * r) * 64;
        const float* wx = wy + 64;
        const float* wm = lw + (14 + r) * 64;
        const float* inc_ = inb + (size_t)r * HWP;
        float oy = pw_b[2 * r], ox = pw_b[2 * r + 1], om = pw_b[14 + r];
#pragma unroll
        for (int j = 0; j < 16; ++j) { oy += wy[j] * dwv0[j];      ox += wx[j] * dwv0[j];      om += wm[j] * dwv0[j]; }
#pragma unroll
        for (int j = 0; j < 16; ++j) { oy += wy[16 + j] * dwv1[j]; ox += wx[16 + j] * dwv1[j]; om += wm[16 + j] * dwv1[j]; }
#pragma unroll
        for (int j = 0; j < 16; ++j) { oy += wy[32 + j] * dwv2[j]; ox += wx[32 + j] * dwv2[j]; om += wm[32 + j] * dwv2[j]; }
#pragma unroll
        for (int j = 0; j < 16; ++j) { oy += wy[48 + j] * dwv3[j]; ox += wx[48 + j] * dwv3[j]; om += wm[48 + j] * dwv3[j]; }
        float m = 1.f / (1.f + __expf(-om));
        float py = oy + (float)h;
        float px = ox + (float)wq;
        float y0 = floorf(py), x0 = floorf(px);
        float wyf = py - y0, wxf = px - x0;
        int iy0 = (int)y0, ix0 = (int)x0;
        bool y0v = (iy0 >= 0) && (iy0 < HH);
        bool y1v = (iy0 + 1 >= 0) && (iy0 + 1 < HH);
        bool x0v = (ix0 >= 0) && (ix0 < WW);
        bool x1v = (ix0 + 1 >= 0) && (ix0 + 1 < WW);
        int yc0 = min(max(iy0, 0), HH - 1), yc1 = min(max(iy0 + 1, 0), HH - 1);
        int xc0 = min(max(ix0, 0), WW - 1), xc1 = min(max(ix0 + 1, 0), WW - 1);
        float v00 = 0.f, v01 = 0.f, v10 = 0.f, v11 = 0.f;
        if (y0v) {
            if (x0v) v00 = inc_[yc0 * WW + xc0];
            if (x1v) v01 = inc_[yc0 * WW + xc1];
        }
        if (y1v) {
            if (x0v) v10 = inc_[yc1 * WW + xc0];
            if (x1v) v11 = inc_[yc1 * WW + xc1];
        }
        float s = (v00 * (1.f - wyf) * (1.f - wxf) + v01 * (1.f - wyf) * wxf +
                   v10 * wyf * (1.f - wxf) + v11 * wyf * wxf) * m;
        const float* dt = dcn_wt + (size_t)r * OO;
#pragma unroll
        for (int j = 0; j < 16; ++j) acc0[j] += s * dt[j];
#pragma unroll
        for (int j = 0; j < 16; ++j) acc1[j] += s * dt[16 + j];
#pragma unroll
        for (int j = 0; j < 16; ++j) acc2[j] += s * dt[32 + j];
#pragma unroll
        for (int j = 0; j < 16; ++j) acc3[j] += s * dt[48 + j];
    }
    float* op = outbuf + (size_t)(b * 3 * OO) * HWP + p;
#pragma unroll
    for (int j = 0; j < 16; ++j) { float v = acc0[j] + dcn_b[j];      op[(size_t)j * HWP] = v > 0.f ? v : 0.f; }
#pragma unroll
    for (int j = 0; j < 16; ++j) { float v = acc1[j] + dcn_b[16 + j]; op[(size_t)(16 + j) * HWP] = v > 0.f ? v : 0.f; }
#pragma unroll
    for (int j = 0; j < 16; ++j) { float v = acc2[j] + dcn_b[32 + j]; op[(size_t)(32 + j) * HWP] = v > 0.f ? v : 0.f; }
#pragma unroll
    for (int j = 0; j < 16; ++j) { float v = acc3[j] + dcn_b[48 + j]; op[(size_t)(48 + j) * HWP] = v > 0.f ? v : 0.f; }
}

// ---------------- attention: output-split x2 partial sums -----------------
// partial layout: [((b*PIX_BLOCKS+pb)*2+g)*32 + o32], output ch = g*32+o32
__global__ __launch_bounds__(256)
void attn_sum_kernel(const float* __restrict__ outbuf, const float* __restrict__ attn_wt,
                     const float* __restrict__ attn_b, float* __restrict__ partial) {
    int g = blockIdx.x & 1;
    int blk = blockIdx.x >> 1;
    int b = blk / PIX_BLOCKS;
    int pb = blk % PIX_BLOCKS;
    int p = pb * 256 + threadIdx.x;
    const float* ob = outbuf + (size_t)(b * 192) * HWP + p;
    f32x16 a0, a1;
#pragma unroll
    for (int j = 0; j < 16; ++j) { a0[j] = attn_b[g * 32 + j]; a1[j] = attn_b[g * 32 + 16 + j]; }
    for (int c = 0; c < 192; ++c) {
        float v = ob[(size_t)c * HWP];
        const float* wt = attn_wt + c * OO + g * 32;
#pragma unroll
        for (int j = 0; j < 16; ++j) a0[j] += v * wt[j];
#pragma unroll
        for (int j = 0; j < 16; ++j) a1[j] += v * wt[16 + j];
    }
    __shared__ float red[4][32];
    int lane = threadIdx.x & 63, wv = threadIdx.x >> 6;
#pragma unroll
    for (int o = 0; o < 32; ++o) {
        float v = (o < 16) ? a0[o] : a1[o - 16];
        v = v > 0.f ? v : 0.f;
        v += __shfl_down(v, 32);
        v += __shfl_down(v, 16);
        v += __shfl_down(v, 8);
        v += __shfl_down(v, 4);
        v += __shfl_down(v, 2);
        v += __shfl_down(v, 1);
        if (lane == 0) red[wv][o] = v;
    }
    __syncthreads();
    if (threadIdx.x < 32) {
        int o = threadIdx.x;
        partial[((size_t)(b * PIX_BLOCKS + pb) * 2 + g) * 32 + o] =
            red[0][o] + red[1][o] + red[2][o] + red[3][o];
    }
}

// ---------------- attention finish ----------------
__global__ void attn_finish_kernel(const float* __restrict__ partial,
                                   const float* __restrict__ fc_w, const float* __restrict__ fc_b,
                                   const float* __restrict__ fcs_w0, const float* __restrict__ fcs_b0,
                                   const float* __restrict__ fcs_w1, const float* __restrict__ fcs_b1,
                                   const float* __restrict__ fcs_w2, const float* __restrict__ fcs_b2,
                                   float* __restrict__ atts) {
    int b = blockIdx.x;
    __shared__ float attm[OO];
    __shared__ float fcv[32];
    int tid = threadIdx.x;
    if (tid < OO) {
        int g = tid >> 5, o = tid & 31;
        float s = 0.f;
        for (int blk = 0; blk < PIX_BLOCKS; ++blk)
            s += partial[((size_t)(b * PIX_BLOCKS + blk) * 2 + g) * 32 + o];
        attm[tid] = s / (float)HWP;
    }
    __syncthreads();
    if (tid < 32) {
        float s = fc_b[tid];
        for (int o = 0; o < OO; ++o) s += fc_w[tid * OO + o] * attm[o];
        fcv[tid] = s > 0.f ? s : 0.f;
    }
    __syncthreads();
    if (tid < OO) {
        {
            float s = fcs_b0[tid];
            for (int j = 0; j < 32; ++j) s += fcs_w0[tid * 32 + j] * fcv[j];
            atts[b * 192 + 0 * OO + tid] = s;
        }
        {
            float s = fcs_b1[tid];
            for (int j = 0; j < 32; ++j) s += fcs_w1[tid * 32 + j] * fcv[j];
            atts[b * 192 + 1 * OO + tid] = s;
        }
        {
            float s = fcs_b2[tid];
            for (int j = 0; j < 32; ++j) s += fcs_w2[tid * 32 + j] * fcv[j];
            atts[b * 192 + 2 * OO + tid] = s;
        }
    }
}

// ---------------- final: scale + 1x1 conv + relu, output-split x2 ---------
__global__ __launch_bounds__(256)
void final_kernel(const float* __restrict__ outbuf, const float* __restrict__ atts,
                  const float* __restrict__ conv_wt, const float* __restrict__ conv_b,
                  float* __restrict__ out) {
    int g = blockIdx.x & 1;
    int blk = blockIdx.x >> 1;
    int b = blk / PIX_BLOCKS;
    int p = (blk % PIX_BLOCKS) * 256 + threadIdx.x;
    const float* ob = outbuf + (size_t)(b * 192) * HWP + p;
    const float* at = atts + b * 192;
    f32x16 a0, a1;
#pragma unroll
    for (int j = 0; j < 16; ++j) { a0[j] = conv_b[g * 32 + j]; a1[j] = conv_b[g * 32 + 16 + j]; }
    for (int c = 0; c < 192; ++c) {
        float v = ob[(size_t)c * HWP] * at[c];
        const float* wt = conv_wt + c * OO + g * 32;
#pragma unroll
        for (int j = 0; j < 16; ++j) a0[j] += v * wt[j];
#pragma unroll
        for (int j = 0; j < 16; ++j) a1[j] += v * wt[16 + j];
    }
    float* op = out + ((size_t)(b * OO) + g * 32) * HWP + p;
#pragma unroll
    for (int j = 0; j < 16; ++j) op[(size_t)j * HWP] = a0[j] > 0.f ? a0[j] : 0.f;
#pragma unroll
    for (int j = 0; j < 16; ++j) op[(size_t)(16 + j) * HWP] = a1[j] > 0.f ? a1[j] : 0.f;
}

extern "C" void kernel_launch(void* const* d_in, const int* in_sizes, int n_in,
                              void* d_out, int out_size, void* d_ws, size_t ws_size,
                              hipStream_t stream) {
    const float* fea    = (const float*)d_in[0];
    const float* inputs = (const float*)d_in[1];
    const float* dw_w[3]  = {(const float*)d_in[2],  (const float*)d_in[8],  (const float*)d_in[14]};
    const float* dw_b[3]  = {(const float*)d_in[3],  (const float*)d_in[9],  (const float*)d_in[15]};
    const float* pw_w[3]  = {(const float*)d_in[4],  (const float*)d_in[10], (const float*)d_in[16]};
    const float* pw_b[3]  = {(const float*)d_in[5],  (const float*)d_in[11], (const float*)d_in[17]};
    const float* dcn_w[3] = {(const float*)d_in[6],  (const float*)d_in[12], (const float*)d_in[18]};
    const float* dcn_b[3] = {(const float*)d_in[7],  (const float*)d_in[13], (const float*)d_in[19]};
    const float* attn_w = (const float*)d_in[20];
    const float* attn_b = (const float*)d_in[21];
    const float* fc_w   = (const float*)d_in[22];
    const float* fc_b   = (const float*)d_in[23];
    const float* fcs_w[3] = {(const float*)d_in[24], (const float*)d_in[26], (const float*)d_in[28]};
    const float* fcs_b[3] = {(const float*)d_in[25], (const float*)d_in[27], (const float*)d_in[29]};
    const float* conv_w = (const float*)d_in[30];
    const float* conv_b = (const float*)d_in[31];
    float* out = (float*)d_out;

    const size_t F_OUTBUF = (size_t)BB * 3 * OO * HWP;   // 28,311,552
    const size_t F_SMALL  = 36864 + 768 + 512 + 4096 + 11264 + 12288 + 12288;
    float* W = (float*)d_ws;
    float* outbuf = W;            W += F_OUTBUF;
    float* om = W;
    size_t avail = (ws_size / 4 > F_OUTBUF + F_SMALL) ? (ws_size / 4 - F_OUTBUF - F_SMALL) : 0;
    int T = (int)(avail / (3 * (size_t)NTOT));
    if (T > 175) T = 175;
    if (T < 1) T = 1;
    float* S = om + (size_t)3 * T * NTOT;
    float* partial = S;           S += 36864;
    float* atts = S;              S += 768;
    float* dcn_wt0 = S;           S += 512;
    float* dcn_wt1 = S;           S += 4096;
    float* dcn_wt2 = S;           S += 11264;
    float* attn_wt = S;           S += 12288;
    float* conv_wt = S;           S += 12288;
    float* dwscr = out;           // d_out as dw-plane scratch; final_kernel rewrites d_out

    transpose_kernel<<<(192 * 64 + 255) / 256, 256, 0, stream>>>(attn_w, attn_wt, 64, 192);
    transpose_kernel<<<(192 * 64 + 255) / 256, 256, 0, stream>>>(conv_w, conv_wt, 64, 192);
    transpose_kernel<<<(7 * 64 + 255) / 256, 256, 0, stream>>>(dcn_w[0], dcn_wt0, 64, 7);
    transpose_kernel<<<(63 * 64 + 255) / 256, 256, 0, stream>>>(dcn_w[1], dcn_wt1, 64, 63);
    transpose_kernel<<<(175 * 64 + 255) / 256, 256, 0, stream>>>(dcn_w[2], dcn_wt2, 64, 175);

    const int dwv_grid = (BB * CF * HH * 48) / 256;   // 9216
    const int pix_grid = BB * PIX_BLOCKS;             // 576
    const int samp_grid = 2 * (NTOT / 256);           // 1152 (channel-split x2)
    const int ntiles = NTOT / 128;                    // 1152

    // ---- k=5 branch ----
    dwv_kernel<5><<<dwv_grid, 256, 0, stream>>>(fea, dw_w[2], dw_b[2], dwscr);
    {
        const int TT = 175;
        for (int t0 = 0; t0 < TT; t0 += T) {
            int t1 = (t0 + T < TT) ? (t0 + T) : TT;
            int Tc = t1 - t0, M = 3 * Tc;
            int mt = (M + 63) / 64;
            pw_gemm_kernel<<<mt * ntiles, 256, 0, stream>>>(pw_w[2], pw_b[2], dwscr, om,
                                                            2 * t0, 2 * Tc, 2 * TT + t0, M);
            int flags = (t0 == 0 ? 1 : 0) | (t1 == TT ? 2 : 0);
            dcn_sample_kernel<5><<<samp_grid, 256, 0, stream>>>(om, inputs, dcn_wt2, dcn_b[2],
                                                                outbuf, 2, t0, t1, flags);
        }
    }
    // ---- k=3 branch ----
    dwv_kernel<3><<<dwv_grid, 256, 0, stream>>>(fea, dw_w[1], dw_b[1], dwscr);
    {
        const int TT = 63;
        for (int t0 = 0; t0 < TT; t0 += T) {
            int t1 = (t0 + T < TT) ? (t0 + T) : TT;
            int Tc = t1 - t0, M = 3 * Tc;
            int mt = (M + 63) / 64;
            pw_gemm_kernel<<<mt * ntiles, 256, 0, stream>>>(pw_w[1], pw_b[1], dwscr, om,
                                                            2 * t0, 2 * Tc, 2 * TT + t0, M);
            int flags = (t0 == 0 ? 1 : 0) | (t1 == TT ? 2 : 0);
            dcn_sample_kernel<3><<<samp_grid, 256, 0, stream>>>(om, inputs, dcn_wt1, dcn_b[1],
                                                                outbuf, 1, t0, t1, flags);
        }
    }
    // ---- k=1 branch ----
    branch_k1_kernel<<<pix_grid, 256, 0, stream>>>(fea, dw_w[0], dw_b[0], pw_w[0], pw_b[0],
                                                   inputs, dcn_wt0, dcn_b[0], outbuf);

    // ---- attention + final ----
    attn_sum_kernel<<<2 * pix_grid, 256, 0, stream>>>(outbuf, attn_wt, attn_b, partial);
    attn_finish_kernel<<<BB, 64, 0, stream>>>(partial, fc_w, fc_b,
                                              fcs_w[0], fcs_b[0], fcs_w[1], fcs_b[1],
                                              fcs_w[2], fcs_b[2], atts);
    final_kernel<<<2 * pix_grid, 256, 0, stream>>>(outbuf, atts, conv_wt, conv_b, out);
}

// Round 10
// 741.286 us; speedup vs baseline: 2.5334x; 1.1036x over previous
//
#include <hip/hip_runtime.h>
#include <math.h>

#define HH 192
#define WW 192
#define HWP (192*192)
#define BB 4
#define CF 64
#define NC 7
#define OO 64
#define NTOT (BB*HWP)          // 147456
#define PIX_BLOCKS (HWP/256)   // 144

typedef float f32x16 __attribute__((ext_vector_type(16)));
typedef float f32x4  __attribute__((ext_vector_type(4)));

// ---------------- vectorized depthwise conv: 4 outputs/thread -------------
template<int k>
__global__ __launch_bounds__(256)
void dwv_kernel(const float* __restrict__ fea, const float* __restrict__ w,
                const float* __restrict__ bias, float* __restrict__ out) {
    constexpr int pad = k / 2;
    int idx = blockIdx.x * 256 + threadIdx.x;      // over B*CF*HH*48
    int xq = idx % 48;
    int x0 = xq * 4;
    int hpos = (idx / 48) % HH;
    int plane = idx / (48 * HH);                   // uniform per block
    int c = plane % CF;
    const float* f = fea + (size_t)plane * HWP;

    float wk[k * k];
#pragma unroll
    for (int i = 0; i < k * k; ++i) wk[i] = w[c * k * k + i];

    float acc0 = 0.f, acc1 = 0.f, acc2 = 0.f, acc3 = 0.f;
#pragma unroll
    for (int dy = 0; dy < k; ++dy) {
        int y = hpos + dy - pad;
        if (y < 0 || y >= HH) continue;
        const float* row = f + y * WW;
        float4 q0 = (x0 >= 4) ? *(const float4*)(row + x0 - 4) : make_float4(0.f, 0.f, 0.f, 0.f);
        float4 q1 = *(const float4*)(row + x0);
        float4 q2 = (x0 + 4 < WW) ? *(const float4*)(row + x0 + 4) : make_float4(0.f, 0.f, 0.f, 0.f);
        float wnd[8] = {q0.z, q0.w, q1.x, q1.y, q1.z, q1.w, q2.x, q2.y};
#pragma unroll
        for (int dx = 0; dx < k; ++dx) {
            float wt = wk[dy * k + dx];
            acc0 += wnd[0 + dx + 2 - pad] * wt;
            acc1 += wnd[1 + dx + 2 - pad] * wt;
            acc2 += wnd[2 + dx + 2 - pad] * wt;
            acc3 += wnd[3 + dx + 2 - pad] * wt;
        }
    }
    float b = bias[c];
    float4 o = make_float4(acc0 + b, acc1 + b, acc2 + b, acc3 + b);
    *(float4*)(out + (size_t)plane * HWP + hpos * WW + x0) = o;
}

// ---------------- generic small transpose ----------------
__global__ void transpose_kernel(const float* __restrict__ in, float* __restrict__ out,
                                 int rows, int cols) {
    int idx = blockIdx.x * 256 + threadIdx.x;
    if (idx >= rows * cols) return;
    int r = idx / cols, c = idx % cols;
    out[c * rows + r] = in[idx];
}

// ---------------- pw GEMM: om[m][NTOT] = pw_w[src(m)][:] @ dw + pw_b -------
__global__ __launch_bounds__(256)
void pw_gemm_kernel(const float* __restrict__ pw_w, const float* __restrict__ pw_b,
                    const float* __restrict__ dw, float* __restrict__ om,
                    int src0, int n_yx, int src1, int M) {
    __shared__ float As[64][68];
    __shared__ float Bs[64][132];
    const int ntiles = NTOT / 128;
    int ntile = blockIdx.x % ntiles;
    int mtile = blockIdx.x / ntiles;
    int nb0 = ntile * 128;
    int mb0 = mtile * 64;
    int tid = threadIdx.x;

    {
        int m = tid & 63;
        int kq = tid >> 6;
        int gm = mb0 + m;
        int srow = (gm < M) ? ((gm < n_yx) ? (src0 + gm) : (src1 + (gm - n_yx))) : src0;
        const float* ap = pw_w + (size_t)srow * CF;
#pragma unroll
        for (int i = 0; i < 4; ++i) {
            int k0 = (kq * 4 + i) * 4;
            float4 v = *(const float4*)(ap + k0);
            As[k0 + 0][m] = v.x; As[k0 + 1][m] = v.y;
            As[k0 + 2][m] = v.z; As[k0 + 3][m] = v.w;
        }
    }
    {
        int b = nb0 / HWP;
        int p0 = nb0 % HWP;
        const float* bp = dw + (size_t)b * CF * HWP + p0;
#pragma unroll
        for (int i = 0; i < 8; ++i) {
            int idx = tid + i * 256;
            int kk = idx >> 5;
            int f4 = idx & 31;
            float4 v = *(const float4*)(bp + (size_t)kk * HWP + f4 * 4);
            *(float4*)&Bs[kk][f4 * 4] = v;
        }
    }
    __syncthreads();

    int tm = (tid & 15) * 4;
    int tn = (tid >> 4) * 8;
    f32x4 aA0 = 0.f, aA1 = 0.f, aB0 = 0.f, aB1 = 0.f;
    f32x4 aC0 = 0.f, aC1 = 0.f, aD0 = 0.f, aD1 = 0.f;
#pragma unroll 8
    for (int kk = 0; kk < 64; ++kk) {
        f32x4 a  = *(const f32x4*)&As[kk][tm];
        f32x4 b0 = *(const f32x4*)&Bs[kk][tn];
        f32x4 b1 = *(const f32x4*)&Bs[kk][tn + 4];
#pragma unroll
        for (int j = 0; j < 4; ++j) {
            aA0[j] += a[0] * b0[j];  aA1[j] += a[0] * b1[j];
            aB0[j] += a[1] * b0[j];  aB1[j] += a[1] * b1[j];
            aC0[j] += a[2] * b0[j];  aC1[j] += a[2] * b1[j];
            aD0[j] += a[3] * b0[j];  aD1[j] += a[3] * b1[j];
        }
    }
    {
        int gm = mb0 + tm;
        float* dst = om + (size_t)gm * NTOT + nb0 + tn;
        if (gm < M) {
            float bi = pw_b[(gm < n_yx) ? (src0 + gm) : (src1 + gm - n_yx)];
#pragma unroll
            for (int j = 0; j < 4; ++j) { dst[j] = aA0[j] + bi; dst[4 + j] = aA1[j] + bi; }
        }
        gm++; dst += NTOT;
        if (gm < M) {
            float bi = pw_b[(gm < n_yx) ? (src0 + gm) : (src1 + gm - n_yx)];
#pragma unroll
            for (int j = 0; j < 4; ++j) { dst[j] = aB0[j] + bi; dst[4 + j] = aB1[j] + bi; }
        }
        gm++; dst += NTOT;
        if (gm < M) {
            float bi = pw_b[(gm < n_yx) ? (src0 + gm) : (src1 + gm - n_yx)];
#pragma unroll
            for (int j = 0; j < 4; ++j) { dst[j] = aC0[j] + bi; dst[4 + j] = aC1[j] + bi; }
        }
        gm++; dst += NTOT;
        if (gm < M) {
            float bi = pw_b[(gm < n_yx) ? (src0 + gm) : (src1 + gm - n_yx)];
#pragma unroll
            for (int j = 0; j < 4; ++j) { dst[j] = aD0[j] + bi; dst[4 + j] = aD1[j] + bi; }
        }
    }
}

// ---------------- sampling only: s[tap][pixel], no channel work -----------
// Round-9 lesson: sampling (~200 ops/tap) dominates FMA (64/tap); it must be
// computed once per (pixel,tap). Taps are independent -> ILP; tap-range split
// x2 across blocks (disjoint writes) for wave count without duplication.
template<int k>
__global__ __launch_bounds__(256)
void sample_kernel(const float* __restrict__ om, const float* __restrict__ inputs,
                   float* __restrict__ sbuf, int t0, int t1) {
    constexpr int K = k * k;
    constexpr int pad = k / 2;
    const int T = t1 - t0;
    int g = blockIdx.x / (NTOT / 256);
    int nb = blockIdx.x % (NTOT / 256);
    int n = nb * 256 + threadIdx.x;
    int b = n / HWP, p = n % HWP;
    int h = p / WW, wq = p % WW;
    const float* inb = inputs + (size_t)b * NC * HWP;
    int half = (T + 1) >> 1;
    int i0 = g * half;
    int i1 = min(T, i0 + half);
#pragma unroll 2
    for (int i = i0; i < i1; ++i) {
        int r = t0 + i;
        float oy = om[(size_t)(2 * i) * NTOT + n];
        float ox = om[(size_t)(2 * i + 1) * NTOT + n];
        float mr = om[(size_t)(2 * T + i) * NTOT + n];
        int c = r / K;
        int kk = r - c * K;
        int ky = kk / k, kx = kk - ky * k;
        const float* inc_ = inb + (size_t)c * HWP;
        float m = 1.f / (1.f + __expf(-mr));
        float py = oy + (float)(ky + h - pad);
        float px = ox + (float)(kx + wq - pad);
        float y0 = floorf(py), x0 = floorf(px);
        float wyf = py - y0, wxf = px - x0;
        int iy0 = (int)y0, ix0 = (int)x0;
        bool y0v = (iy0 >= 0) && (iy0 < HH);
        bool y1v = (iy0 + 1 >= 0) && (iy0 + 1 < HH);
        bool x0v = (ix0 >= 0) && (ix0 < WW);
        bool x1v = (ix0 + 1 >= 0) && (ix0 + 1 < WW);
        int yc0 = min(max(iy0, 0), HH - 1), yc1 = min(max(iy0 + 1, 0), HH - 1);
        int xc0 = min(max(ix0, 0), WW - 1), xc1 = min(max(ix0 + 1, 0), WW - 1);
        float v00 = 0.f, v01 = 0.f, v10 = 0.f, v11 = 0.f;
        if (y0v) {
            if (x0v) v00 = inc_[yc0 * WW + xc0];
            if (x1v) v01 = inc_[yc0 * WW + xc1];
        }
        if (y1v) {
            if (x0v) v10 = inc_[yc1 * WW + xc0];
            if (x1v) v11 = inc_[yc1 * WW + xc1];
        }
        float s = (v00 * (1.f - wyf) * (1.f - wxf) + v01 * (1.f - wyf) * wxf +
                   v10 * wyf * (1.f - wxf) + v11 * wyf * wxf) * m;
        sbuf[(size_t)i * NTOT + n] = s;
    }
}

// ---------------- accumulation GEMM: outbuf[64][N] (+)= wt^T @ s ----------
// flags: 1 = first chunk (init acc), 2 = last chunk (add bias + relu).
__global__ __launch_bounds__(256)
void acc_gemm_kernel(const float* __restrict__ wt,     // [T_all][64]
                     const float* __restrict__ bias,
                     const float* __restrict__ sbuf,   // [T][NTOT] chunk-local
                     float* __restrict__ outbuf, int t_slot,
                     int t0, int t1, int flags) {
    __shared__ float As[64][68];    // [k][ch]
    __shared__ float Bs[64][132];   // [k][px]
    const int T = t1 - t0;          // <= 64
    int nb0 = blockIdx.x * 128;
    int tid = threadIdx.x;

    for (int i4 = tid; i4 < T * 16; i4 += 256) {
        int row = i4 >> 4, c4 = (i4 & 15) * 4;
        float4 v = *(const float4*)(wt + (size_t)(t0 + row) * OO + c4);
        As[row][c4] = v.x; As[row][c4 + 1] = v.y; As[row][c4 + 2] = v.z; As[row][c4 + 3] = v.w;
    }
    for (int i4 = tid; i4 < T * 32; i4 += 256) {
        int row = i4 >> 5, f4 = (i4 & 31) * 4;
        float4 v = *(const float4*)(sbuf + (size_t)row * NTOT + nb0 + f4);
        *(float4*)&Bs[row][f4] = v;
    }
    __syncthreads();

    int tm = (tid & 15) * 4;   // channel
    int tn = (tid >> 4) * 8;   // pixel
    f32x4 aA0 = 0.f, aA1 = 0.f, aB0 = 0.f, aB1 = 0.f;
    f32x4 aC0 = 0.f, aC1 = 0.f, aD0 = 0.f, aD1 = 0.f;
#pragma unroll 2
    for (int kk = 0; kk < T; ++kk) {
        f32x4 a  = *(const f32x4*)&As[kk][tm];
        f32x4 b0 = *(const f32x4*)&Bs[kk][tn];
        f32x4 b1 = *(const f32x4*)&Bs[kk][tn + 4];
#pragma unroll
        for (int j = 0; j < 4; ++j) {
            aA0[j] += a[0] * b0[j];  aA1[j] += a[0] * b1[j];
            aB0[j] += a[1] * b0[j];  aB1[j] += a[1] * b1[j];
            aC0[j] += a[2] * b0[j];  aC1[j] += a[2] * b1[j];
            aD0[j] += a[3] * b0[j];  aD1[j] += a[3] * b1[j];
        }
    }

    int b = nb0 / HWP, p0 = nb0 % HWP;
    f32x4 accs[8] = {aA0, aA1, aB0, aB1, aC0, aC1, aD0, aD1};
#pragma unroll
    for (int row = 0; row < 4; ++row) {
        int ch = tm + row;
        float* ptr = outbuf + ((size_t)((b * 3 + t_slot) * OO + ch)) * HWP + p0 + tn;
        f32x4 lo = accs[row * 2], hi = accs[row * 2 + 1];
        if (!(flags & 1)) {
            f32x4 o0 = *(const f32x4*)ptr;
            f32x4 o1 = *(const f32x4*)(ptr + 4);
#pragma unroll
            for (int j = 0; j < 4; ++j) { lo[j] += o0[j]; hi[j] += o1[j]; }
        }
        if (flags & 2) {
            float bi = bias[ch];
#pragma unroll
            for (int j = 0; j < 4; ++j) {
                lo[j] += bi; hi[j] += bi;
                lo[j] = lo[j] > 0.f ? lo[j] : 0.f;
                hi[j] = hi[j] > 0.f ? hi[j] : 0.f;
            }
        }
        *(f32x4*)ptr = lo;
        *(f32x4*)(ptr + 4) = hi;
    }
}

// ---------------- k=1 branch: fused elementwise dw + 7-tap deform ---------
__global__ __launch_bounds__(256)
void branch_k1_kernel(const float* __restrict__ fea,
                      const float* __restrict__ dw_w0, const float* __restrict__ dw_b0,
                      const float* __restrict__ pw_w, const float* __restrict__ pw_b,
                      const float* __restrict__ inputs,
                      const float* __restrict__ dcn_wt, const float* __restrict__ dcn_b,
                      float* __restrict__ outbuf) {
    __shared__ float lw[21 * 64];
    for (int i = threadIdx.x; i < 21 * 16; i += 256)
        ((float4*)lw)[i] = ((const float4*)pw_w)[i];
    __syncthreads();
    int gid = blockIdx.x;
    int b = gid / PIX_BLOCKS;
    int p = (gid % PIX_BLOCKS) * 256 + threadIdx.x;
    int h = p / WW, wq = p % WW;
    const float* inb = inputs + (size_t)b * NC * HWP;

    f32x16 dwv0, dwv1, dwv2, dwv3;
    {
        const float* fp = fea + (size_t)(b * CF) * HWP + p;
#pragma unroll
        for (int j = 0; j < 16; ++j) dwv0[j] = fp[(size_t)j * HWP] * dw_w0[j] + dw_b0[j];
#pragma unroll
        for (int j = 0; j < 16; ++j) dwv1[j] = fp[(size_t)(16 + j) * HWP] * dw_w0[16 + j] + dw_b0[16 + j];
#pragma unroll
        for (int j = 0; j < 16; ++j) dwv2[j] = fp[(size_t)(32 + j) * HWP] * dw_w0[32 + j] + dw_b0[32 + j];
#pragma unroll
        for (int j = 0; j < 16; ++j) dwv3[j] = fp[(size_t)(48 + j) * HWP] * dw_w0[48 + j] + dw_b0[48 + j];
    }
    f32x16 acc0, acc1, acc2, acc3;
#pragma unroll
    for (int j = 0; j < 16; ++j) { acc0[j] = 0.f; acc1[j] = 0.f; acc2[j] = 0.f; acc3[j] = 0.f; }

    for (int r = 0; r < NC; ++r) {
        const float* wy = lw + (2 * r) * 64;
        const float* wx = wy + 64;
        const float* wm = lw + (14 + r) * 64;
        const float* inc_ = inb + (size_t)r * HWP;
        float oy = pw_b[2 * r], ox = pw_b[2 * r + 1], om = pw_b[14 + r];
#pragma unroll
        for (int j = 0; j < 16; ++j) { oy += wy[j] * dwv0[j];      ox += wx[j] * dwv0[j];      om += wm[j] * dwv0[j]; }
#pragma unroll
        for (int j = 0; j < 16; ++j) { oy += wy[16 + j] * dwv1[j]; ox += wx[16 + j] * dwv1[j]; om += wm[16 + j] * dwv1[j]; }
#pragma unroll
        for (int j = 0; j < 16; ++j) { oy += wy[32 + j] * dwv2[j]; ox += wx[32 + j] * dwv2[j]; om += wm[32 + j] * dwv2[j]; }
#pragma unroll
        for (int j = 0; j < 16; ++j) { oy += wy[48 + j] * dwv3[j]; ox += wx[48 + j] * dwv3[j]; om += wm[48 + j] * dwv3[j]; }
        float m = 1.f / (1.f + __expf(-om));
        float py = oy + (float)h;
        float px = ox + (float)wq;
        float y0 = floorf(py), x0 = floorf(px);
        float wyf = py - y0, wxf = px - x0;
        int iy0 = (int)y0, ix0 = (int)x0;
        bool y0v = (iy0 >= 0) && (iy0 < HH);
        bool y1v = (iy0 + 1 >= 0) && (iy0 + 1 < HH);
        bool x0v = (ix0 >= 0) && (ix0 < WW);
        bool x1v = (ix0 + 1 >= 0) && (ix0 + 1 < WW);
        int yc0 = min(max(iy0, 0), HH - 1), yc1 = min(max(iy0 + 1, 0), HH - 1);
        int xc0 = min(max(ix0, 0), WW - 1), xc1 = min(max(ix0 + 1, 0), WW - 1);
        float v00 = 0.f, v01 = 0.f, v10 = 0.f, v11 = 0.f;
        if (y0v) {
            if (x0v) v00 = inc_[yc0 * WW + xc0];
            if (x1v) v01 = inc_[yc0 * WW + xc1];
        }
        if (y1v) {
            if (x0v) v10 = inc_[yc1 * WW + xc0];
            if (x1v) v11 = inc_[yc1 * WW + xc1];
        }
        float s = (v00 * (1.f - wyf) * (1.f - wxf) + v01 * (1.f - wyf) * wxf +
                   v10 * wyf * (1.f - wxf) + v11 * wyf * wxf) * m;
        const float* dt = dcn_wt + (size_t)r * OO;
#pragma unroll
        for (int j = 0; j < 16; ++j) acc0[j] += s * dt[j];
#pragma unroll
        for (int j = 0; j < 16; ++j) acc1[j] += s * dt[16 + j];
#pragma unroll
        for (int j = 0; j < 16; ++j) acc2[j] += s * dt[32 + j];
#pragma unroll
        for (int j = 0; j < 16; ++j) acc3[j] += s * dt[48 + j];
    }
    float* op = outbuf + (size_t)(b * 3 * OO) * HWP + p;
#pragma unroll
    for (int j = 0; j < 16; ++j) { float v = acc0[j] + dcn_b[j];      op[(size_t)j * HWP] = v > 0.f ? v : 0.f; }
#pragma unroll
    for (int j = 0; j < 16; ++j) { float v = acc1[j] + dcn_b[16 + j]; op[(size_t)(16 + j) * HWP] = v > 0.f ? v : 0.f; }
#pragma unroll
    for (int j = 0; j < 16; ++j) { float v = acc2[j] + dcn_b[32 + j]; op[(size_t)(32 + j) * HWP] = v > 0.f ? v : 0.f; }
#pragma unroll
    for (int j = 0; j < 16; ++j) { float v = acc3[j] + dcn_b[48 + j]; op[(size_t)(48 + j) * HWP] = v > 0.f ? v : 0.f; }
}

// ---------------- attention: output-split x2 partial sums -----------------
__global__ __launch_bounds__(256)
void attn_sum_kernel(const float* __restrict__ outbuf, const float* __restrict__ attn_wt,
                     const float* __restrict__ attn_b, float* __restrict__ partial) {
    int g = blockIdx.x & 1;
    int blk = blockIdx.x >> 1;
    int b = blk / PIX_BLOCKS;
    int pb = blk % PIX_BLOCKS;
    int p = pb * 256 + threadIdx.x;
    const float* ob = outbuf + (size_t)(b * 192) * HWP + p;
    f32x16 a0, a1;
#pragma unroll
    for (int j = 0; j < 16; ++j) { a0[j] = attn_b[g * 32 + j]; a1[j] = attn_b[g * 32 + 16 + j]; }
    for (int c = 0; c < 192; ++c) {
        float v = ob[(size_t)c * HWP];
        const float* wt = attn_wt + c * OO + g * 32;
#pragma unroll
        for (int j = 0; j < 16; ++j) a0[j] += v * wt[j];
#pragma unroll
        for (int j = 0; j < 16; ++j) a1[j] += v * wt[16 + j];
    }
    __shared__ float red[4][32];
    int lane = threadIdx.x & 63, wv = threadIdx.x >> 6;
#pragma unroll
    for (int o = 0; o < 32; ++o) {
        float v = (o < 16) ? a0[o] : a1[o - 16];
        v = v > 0.f ? v : 0.f;
        v += __shfl_down(v, 32);
        v += __shfl_down(v, 16);
        v += __shfl_down(v, 8);
        v += __shfl_down(v, 4);
        v += __shfl_down(v, 2);
        v += __shfl_down(v, 1);
        if (lane == 0) red[wv][o] = v;
    }
    __syncthreads();
    if (threadIdx.x < 32) {
        int o = threadIdx.x;
        partial[((size_t)(b * PIX_BLOCKS + pb) * 2 + g) * 32 + o] =
            red[0][o] + red[1][o] + red[2][o] + red[3][o];
    }
}

// ---------------- attention finish ----------------
__global__ void attn_finish_kernel(const float* __restrict__ partial,
                                   const float* __restrict__ fc_w, const float* __restrict__ fc_b,
                                   const float* __restrict__ fcs_w0, const float* __restrict__ fcs_b0,
                                   const float* __restrict__ fcs_w1, const float* __restrict__ fcs_b1,
                                   const float* __restrict__ fcs_w2, const float* __restrict__ fcs_b2,
                                   float* __restrict__ atts) {
    int b = blockIdx.x;
    __shared__ float attm[OO];
    __shared__ float fcv[32];
    int tid = threadIdx.x;
    if (tid < OO) {
        int g = tid >> 5, o = tid & 31;
        float s = 0.f;
        for (int blk = 0; blk < PIX_BLOCKS; ++blk)
            s += partial[((size_t)(b * PIX_BLOCKS + blk) * 2 + g) * 32 + o];
        attm[tid] = s / (float)HWP;
    }
    __syncthreads();
    if (tid < 32) {
        float s = fc_b[tid];
        for (int o = 0; o < OO; ++o) s += fc_w[tid * OO + o] * attm[o];
        fcv[tid] = s > 0.f ? s : 0.f;
    }
    __syncthreads();
    if (tid < OO) {
        {
            float s = fcs_b0[tid];
            for (int j = 0; j < 32; ++j) s += fcs_w0[tid * 32 + j] * fcv[j];
            atts[b * 192 + 0 * OO + tid] = s;
        }
        {
            float s = fcs_b1[tid];
            for (int j = 0; j < 32; ++j) s += fcs_w1[tid * 32 + j] * fcv[j];
            atts[b * 192 + 1 * OO + tid] = s;
        }
        {
            float s = fcs_b2[tid];
            for (int j = 0; j < 32; ++j) s += fcs_w2[tid * 32 + j] * fcv[j];
            atts[b * 192 + 2 * OO + tid] = s;
        }
    }
}

// ---------------- final: scale + 1x1 conv + relu, output-split x2 ---------
__global__ __launch_bounds__(256)
void final_kernel(const float* __restrict__ outbuf, const float* __restrict__ atts,
                  const float* __restrict__ conv_wt, const float* __restrict__ conv_b,
                  float* __restrict__ out) {
    int g = blockIdx.x & 1;
    int blk = blockIdx.x >> 1;
    int b = blk / PIX_BLOCKS;
    int p = (blk % PIX_BLOCKS) * 256 + threadIdx.x;
    const float* ob = outbuf + (size_t)(b * 192) * HWP + p;
    const float* at = atts + b * 192;
    f32x16 a0, a1;
#pragma unroll
    for (int j = 0; j < 16; ++j) { a0[j] = conv_b[g * 32 + j]; a1[j] = conv_b[g * 32 + 16 + j]; }
    for (int c = 0; c < 192; ++c) {
        float v = ob[(size_t)c * HWP] * at[c];
        const float* wt = conv_wt + c * OO + g * 32;
#pragma unroll
        for (int j = 0; j < 16; ++j) a0[j] += v * wt[j];
#pragma unroll
        for (int j = 0; j < 16; ++j) a1[j] += v * wt[16 + j];
    }
    float* op = out + ((size_t)(b * OO) + g * 32) * HWP + p;
#pragma unroll
    for (int j = 0; j < 16; ++j) op[(size_t)j * HWP] = a0[j] > 0.f ? a0[j] : 0.f;
#pragma unroll
    for (int j = 0; j < 16; ++j) op[(size_t)(16 + j) * HWP] = a1[j] > 0.f ? a1[j] : 0.f;
}

extern "C" void kernel_launch(void* const* d_in, const int* in_sizes, int n_in,
                              void* d_out, int out_size, void* d_ws, size_t ws_size,
                              hipStream_t stream) {
    const float* fea    = (const float*)d_in[0];
    const float* inputs = (const float*)d_in[1];
    const float* dw_w[3]  = {(const float*)d_in[2],  (const float*)d_in[8],  (const float*)d_in[14]};
    const float* dw_b[3]  = {(const float*)d_in[3],  (const float*)d_in[9],  (const float*)d_in[15]};
    const float* pw_w[3]  = {(const float*)d_in[4],  (const float*)d_in[10], (const float*)d_in[16]};
    const float* pw_b[3]  = {(const float*)d_in[5],  (const float*)d_in[11], (const float*)d_in[17]};
    const float* dcn_w[3] = {(const float*)d_in[6],  (const float*)d_in[12], (const float*)d_in[18]};
    const float* dcn_b[3] = {(const float*)d_in[7],  (const float*)d_in[13], (const float*)d_in[19]};
    const float* attn_w = (const float*)d_in[20];
    const float* attn_b = (const float*)d_in[21];
    const float* fc_w   = (const float*)d_in[22];
    const float* fc_b   = (const float*)d_in[23];
    const float* fcs_w[3] = {(const float*)d_in[24], (const float*)d_in[26], (const float*)d_in[28]};
    const float* fcs_b[3] = {(const float*)d_in[25], (const float*)d_in[27], (const float*)d_in[29]};
    const float* conv_w = (const float*)d_in[30];
    const float* conv_b = (const float*)d_in[31];
    float* out = (float*)d_out;

    const size_t F_OUTBUF = (size_t)BB * 3 * OO * HWP;   // 28,311,552
    const size_t F_SMALL  = 36864 + 768 + 512 + 4096 + 11264 + 12288 + 12288;
    float* W = (float*)d_ws;
    float* outbuf = W;            W += F_OUTBUF;
    size_t avail = (ws_size / 4 > F_OUTBUF + F_SMALL) ? (ws_size / 4 - F_OUTBUF - F_SMALL) : 0;
    int T = (int)(avail / (4 * (size_t)NTOT));   // om 3T rows + s T rows
    if (T > 64) T = 64;                          // acc_gemm LDS cap
    if (T < 1) T = 1;
    float* om = W;                W += (size_t)3 * T * NTOT;
    float* sbuf = W;              W += (size_t)T * NTOT;
    float* partial = W;           W += 36864;
    float* atts = W;              W += 768;
    float* dcn_wt0 = W;           W += 512;
    float* dcn_wt1 = W;           W += 4096;
    float* dcn_wt2 = W;           W += 11264;
    float* attn_wt = W;           W += 12288;
    float* conv_wt = W;           W += 12288;
    float* dwscr = out;           // d_out as dw-plane scratch; final_kernel rewrites d_out

    transpose_kernel<<<(192 * 64 + 255) / 256, 256, 0, stream>>>(attn_w, attn_wt, 64, 192);
    transpose_kernel<<<(192 * 64 + 255) / 256, 256, 0, stream>>>(conv_w, conv_wt, 64, 192);
    transpose_kernel<<<(7 * 64 + 255) / 256, 256, 0, stream>>>(dcn_w[0], dcn_wt0, 64, 7);
    transpose_kernel<<<(63 * 64 + 255) / 256, 256, 0, stream>>>(dcn_w[1], dcn_wt1, 64, 63);
    transpose_kernel<<<(175 * 64 + 255) / 256, 256, 0, stream>>>(dcn_w[2], dcn_wt2, 64, 175);

    const int dwv_grid = (BB * CF * HH * 48) / 256;   // 9216
    const int pix_grid = BB * PIX_BLOCKS;             // 576
    const int samp_grid = 2 * (NTOT / 256);           // 1152 (tap-range split x2)
    const int acc_grid = NTOT / 128;                  // 1152
    const int ntiles = NTOT / 128;                    // 1152

    // ---- k=5 branch ----
    dwv_kernel<5><<<dwv_grid, 256, 0, stream>>>(fea, dw_w[2], dw_b[2], dwscr);
    {
        const int TT = 175;
        for (int t0 = 0; t0 < TT; t0 += T) {
            int t1 = (t0 + T < TT) ? (t0 + T) : TT;
            int Tc = t1 - t0, M = 3 * Tc;
            int mt = (M + 63) / 64;
            pw_gemm_kernel<<<mt * ntiles, 256, 0, stream>>>(pw_w[2], pw_b[2], dwscr, om,
                                                            2 * t0, 2 * Tc, 2 * TT + t0, M);
            sample_kernel<5><<<samp_grid, 256, 0, stream>>>(om, inputs, sbuf, t0, t1);
            int flags = (t0 == 0 ? 1 : 0) | (t1 == TT ? 2 : 0);
            acc_gemm_kernel<<<acc_grid, 256, 0, stream>>>(dcn_wt2, dcn_b[2], sbuf, outbuf,
                                                          2, t0, t1, flags);
        }
    }
    // ---- k=3 branch ----
    dwv_kernel<3><<<dwv_grid, 256, 0, stream>>>(fea, dw_w[1], dw_b[1], dwscr);
    {
        const int TT = 63;
        for (int t0 = 0; t0 < TT; t0 += T) {
            int t1 = (t0 + T < TT) ? (t0 + T) : TT;
            int Tc = t1 - t0, M = 3 * Tc;
            int mt = (M + 63) / 64;
            pw_gemm_kernel<<<mt * ntiles, 256, 0, stream>>>(pw_w[1], pw_b[1], dwscr, om,
                                                            2 * t0, 2 * Tc, 2 * TT + t0, M);
            sample_kernel<3><<<samp_grid, 256, 0, stream>>>(om, inputs, sbuf, t0, t1);
            int flags = (t0 == 0 ? 1 : 0) | (t1 == TT ? 2 : 0);
            acc_gemm_kernel<<<acc_grid, 256, 0, stream>>>(dcn_wt1, dcn_b[1], sbuf, outbuf,
                                                          1, t0, t1, flags);
        }
    }
    // ---- k=1 branch ----
    branch_k1_kernel<<<pix_grid, 256, 0, stream>>>(fea, dw_w[0], dw_b[0], pw_w[0], pw_b[0],
                                                   inputs, dcn_wt0, dcn_b[0], outbuf);

    // ---- attention + final ----
    attn_sum_kernel<<<2 * pix_grid, 256, 0, stream>>>(outbuf, attn_wt, attn_b, partial);
    attn_finish_kernel<<<BB, 64, 0, stream>>>(partial, fc_w, fc_b,
                                              fcs_w[0], fcs_b[0], fcs_w[1], fcs_b[1],
                                              fcs_w[2], fcs_b[2], atts);
    final_kernel<<<2 * pix_grid, 256, 0, stream>>>(outbuf, atts, conv_wt, conv_b, out);
}